// Round 1
// baseline (1108.881 us; speedup 1.0000x reference)
//
#include <hip/hip_runtime.h>

#define T_SEQ 4096
#define DM    768
#define NH    12
#define DH    64
#define NC    2304   // 3 * DM

// ---------------------------------------------------------------------------
// Kernel 1: H = X @ W_qkv  (4096x768 @ 768x2304), scatter to Q/K/V [h][t][64].
// 64x64 tile, 256 threads, 4x4 per thread, BK=16. Q pre-scaled by 1/8.
// Each 64-col block is exactly one (head, which) slot: head=cb/3, which=cb%3.
// ---------------------------------------------------------------------------
__global__ __launch_bounds__(256)
void qkv_gemm_kernel(const float* __restrict__ x, const float* __restrict__ w,
                     float* __restrict__ q, float* __restrict__ k,
                     float* __restrict__ v) {
    __shared__ float At[16][68];   // [kk][row] transposed, padded
    __shared__ float Bs[16][64];   // [kk][col]
    const int tid = threadIdx.x;
    const int cb = blockIdx.x;     // 0..35
    const int rb = blockIdx.y;     // 0..63
    const int r0 = (tid >> 4) * 4;
    const int c0 = (tid & 15) * 4;
    const int arow = tid >> 2;         // 0..63
    const int ak4  = (tid & 3) * 4;    // 0,4,8,12
    const int bkk  = tid >> 4;         // 0..15
    const int bc4  = (tid & 15) * 4;

    const int head  = cb / 3;
    const int which = cb % 3;
    float* dst = (which == 0) ? q : (which == 1) ? k : v;
    const float wscale = (which == 0) ? 0.125f : 1.0f;  // 1/sqrt(64)

    float acc[4][4] = {};
    for (int kt = 0; kt < DM / 16; ++kt) {
        float4 av = *(const float4*)(x + (size_t)(rb * 64 + arow) * DM + kt * 16 + ak4);
        float4 bv = *(const float4*)(w + (size_t)(kt * 16 + bkk) * NC + cb * 64 + bc4);
        At[ak4 + 0][arow] = av.x;
        At[ak4 + 1][arow] = av.y;
        At[ak4 + 2][arow] = av.z;
        At[ak4 + 3][arow] = av.w;
        *(float4*)(&Bs[bkk][bc4]) = bv;
        __syncthreads();
        #pragma unroll
        for (int kk = 0; kk < 16; ++kk) {
            float4 a4 = *(const float4*)(&At[kk][r0]);
            float4 b4 = *(const float4*)(&Bs[kk][c0]);
            float aa[4] = {a4.x, a4.y, a4.z, a4.w};
            float bb[4] = {b4.x, b4.y, b4.z, b4.w};
            #pragma unroll
            for (int i = 0; i < 4; ++i)
                #pragma unroll
                for (int j = 0; j < 4; ++j)
                    acc[i][j] = fmaf(aa[i], bb[j], acc[i][j]);
        }
        __syncthreads();
    }
    #pragma unroll
    for (int i = 0; i < 4; ++i) {
        const int t = rb * 64 + r0 + i;
        float4 o;
        o.x = acc[i][0] * wscale;
        o.y = acc[i][1] * wscale;
        o.z = acc[i][2] * wscale;
        o.w = acc[i][3] * wscale;
        *(float4*)(dst + (size_t)(head * T_SEQ + t) * DH + c0) = o;
    }
}

// ---------------------------------------------------------------------------
// Kernel 2: flash attention, causal. Block = (head, 64-row q-block), 256 thr.
// Qt/Kt in LDS transposed [d][r] -> S-phase inner loop = 2x ds_read_b128 per
// 16 FMA, conflict-free. K and V time-share one LDS buffer; V is loaded to
// registers during softmax (latency hidden), written to LDS after barrier.
// LDS = 16K(Qt) + 16K(KV) + 17K(Ss pad 68) + 768B -> ~51 KB, 3 blocks/CU.
// ---------------------------------------------------------------------------
__global__ __launch_bounds__(256)
void attn_kernel(const float* __restrict__ qg, const float* __restrict__ kg,
                 const float* __restrict__ vg, float* __restrict__ att) {
    __shared__ float Qt[64][64];    // [d][r]
    __shared__ float KVs[64][64];   // K phase: [d][c]; V phase: [k][d]
    __shared__ float Ss[64][68];    // [r][c], padded for float4 + conflicts
    __shared__ float m_s[64], l_s[64], al_s[64];

    const int tid = threadIdx.x;
    const int qb = (int)gridDim.x - 1 - (int)blockIdx.x;  // heavy blocks first
    const int h  = blockIdx.y;
    const int sr0 = (tid >> 4) * 4;   // 0..60
    const int sc0 = (tid & 15) * 4;   // 0..60

    // ---- load Q tile transposed: [r][d] global -> Qt[d][r]
    const float* Qp = qg + (size_t)(h * T_SEQ + qb * 64) * DH;
    #pragma unroll
    for (int i = 0; i < 4; ++i) {
        const int e = tid + i * 256;
        const int r = e & 63;
        const int d4 = (e >> 6) * 4;
        float4 t4 = *(const float4*)(Qp + r * DH + d4);
        Qt[d4 + 0][r] = t4.x;
        Qt[d4 + 1][r] = t4.y;
        Qt[d4 + 2][r] = t4.z;
        Qt[d4 + 3][r] = t4.w;
    }
    if (tid < 64) { m_s[tid] = -1e30f; l_s[tid] = 0.0f; }

    float acc[4][4] = {};

    for (int kb = 0; kb <= qb; ++kb) {
        const float* Kp = kg + (size_t)(h * T_SEQ + kb * 64) * DH;
        const float* Vp = vg + (size_t)(h * T_SEQ + kb * 64) * DH;

        // ---- K tile transposed into KVs[d][c]
        #pragma unroll
        for (int i = 0; i < 4; ++i) {
            const int e = tid + i * 256;
            const int r = e & 63;
            const int d4 = (e >> 6) * 4;
            float4 t4 = *(const float4*)(Kp + r * DH + d4);
            KVs[d4 + 0][r] = t4.x;
            KVs[d4 + 1][r] = t4.y;
            KVs[d4 + 2][r] = t4.z;
            KVs[d4 + 3][r] = t4.w;
        }
        __syncthreads();

        // ---- S = Q K^T (scale pre-applied to Q)
        float sacc[4][4] = {};
        #pragma unroll 4
        for (int d = 0; d < 64; ++d) {
            float4 q4 = *(const float4*)(&Qt[d][sr0]);
            float4 k4 = *(const float4*)(&KVs[d][sc0]);
            float aa[4] = {q4.x, q4.y, q4.z, q4.w};
            float bb[4] = {k4.x, k4.y, k4.z, k4.w};
            #pragma unroll
            for (int i = 0; i < 4; ++i)
                #pragma unroll
                for (int j = 0; j < 4; ++j)
                    sacc[i][j] = fmaf(aa[i], bb[j], sacc[i][j]);
        }
        const int qr = qb * 64 + sr0;
        const int kc = kb * 64 + sc0;
        #pragma unroll
        for (int i = 0; i < 4; ++i) {
            float4 o;
            o.x = (kc + 0 <= qr + i) ? sacc[i][0] : -1e30f;
            o.y = (kc + 1 <= qr + i) ? sacc[i][1] : -1e30f;
            o.z = (kc + 2 <= qr + i) ? sacc[i][2] : -1e30f;
            o.w = (kc + 3 <= qr + i) ? sacc[i][3] : -1e30f;
            *(float4*)(&Ss[sr0 + i][sc0]) = o;
        }
        __syncthreads();

        // ---- V tile -> registers (global latency hides under softmax)
        float4 vl[4];
        int vrr[4], vcc[4];
        #pragma unroll
        for (int i = 0; i < 4; ++i) {
            const int e = tid + i * 256;
            vrr[i] = e >> 4;
            vcc[i] = (e & 15) * 4;
            vl[i] = *(const float4*)(Vp + vrr[i] * DH + vcc[i]);
        }
        // ---- online softmax (one thread per row)
        if (tid < 64) {
            const int r = tid;
            float mx = -1e30f;
            #pragma unroll 8
            for (int c = 0; c < 64; ++c) mx = fmaxf(mx, Ss[r][c]);
            const float mold = m_s[r];
            const float mnew = fmaxf(mold, mx);
            const float al = __expf(mold - mnew);
            float sum = 0.0f;
            #pragma unroll 8
            for (int c = 0; c < 64; ++c) {
                const float p = __expf(Ss[r][c] - mnew);
                Ss[r][c] = p;
                sum += p;
            }
            m_s[r] = mnew;
            l_s[r] = fmaf(l_s[r], al, sum);
            al_s[r] = al;
        }
        // ---- V registers -> KVs[k][d]
        #pragma unroll
        for (int i = 0; i < 4; ++i)
            *(float4*)(&KVs[vrr[i]][vcc[i]]) = vl[i];
        __syncthreads();

        // ---- PV: acc = acc*alpha + P @ V
        #pragma unroll
        for (int i = 0; i < 4; ++i) {
            const float a = al_s[sr0 + i];
            acc[i][0] *= a; acc[i][1] *= a; acc[i][2] *= a; acc[i][3] *= a;
        }
        #pragma unroll 2
        for (int k4 = 0; k4 < 64; k4 += 4) {
            float p[4][4], vvv[4][4];
            #pragma unroll
            for (int i = 0; i < 4; ++i) {
                float4 t4 = *(const float4*)(&Ss[sr0 + i][k4]);
                p[i][0] = t4.x; p[i][1] = t4.y; p[i][2] = t4.z; p[i][3] = t4.w;
            }
            #pragma unroll
            for (int m = 0; m < 4; ++m) {
                float4 t4 = *(const float4*)(&KVs[k4 + m][sc0]);
                vvv[m][0] = t4.x; vvv[m][1] = t4.y; vvv[m][2] = t4.z; vvv[m][3] = t4.w;
            }
            #pragma unroll
            for (int i = 0; i < 4; ++i)
                #pragma unroll
                for (int m = 0; m < 4; ++m)
                    #pragma unroll
                    for (int j = 0; j < 4; ++j)
                        acc[i][j] = fmaf(p[i][m], vvv[m][j], acc[i][j]);
        }
        __syncthreads();
    }

    // ---- epilogue: normalize, write att [t][h*64+d]
    #pragma unroll
    for (int i = 0; i < 4; ++i) {
        const float inv = 1.0f / l_s[sr0 + i];
        float4 o;
        o.x = acc[i][0] * inv;
        o.y = acc[i][1] * inv;
        o.z = acc[i][2] * inv;
        o.w = acc[i][3] * inv;
        *(float4*)(att + (size_t)(qb * 64 + sr0 + i) * DM + h * DH + sc0) = o;
    }
}

// ---------------------------------------------------------------------------
// Kernel 3: out = att @ W_proj + b  (4096x768 @ 768x768)
// ---------------------------------------------------------------------------
__global__ __launch_bounds__(256)
void proj_gemm_kernel(const float* __restrict__ a, const float* __restrict__ w,
                      const float* __restrict__ bias, float* __restrict__ out) {
    __shared__ float At[16][68];
    __shared__ float Bs[16][64];
    const int tid = threadIdx.x;
    const int cb = blockIdx.x;     // 0..11
    const int rb = blockIdx.y;     // 0..63
    const int r0 = (tid >> 4) * 4;
    const int c0 = (tid & 15) * 4;
    const int arow = tid >> 2;
    const int ak4  = (tid & 3) * 4;
    const int bkk  = tid >> 4;
    const int bc4  = (tid & 15) * 4;

    float acc[4][4] = {};
    for (int kt = 0; kt < DM / 16; ++kt) {
        float4 av = *(const float4*)(a + (size_t)(rb * 64 + arow) * DM + kt * 16 + ak4);
        float4 bv = *(const float4*)(w + (size_t)(kt * 16 + bkk) * DM + cb * 64 + bc4);
        At[ak4 + 0][arow] = av.x;
        At[ak4 + 1][arow] = av.y;
        At[ak4 + 2][arow] = av.z;
        At[ak4 + 3][arow] = av.w;
        *(float4*)(&Bs[bkk][bc4]) = bv;
        __syncthreads();
        #pragma unroll
        for (int kk = 0; kk < 16; ++kk) {
            float4 a4 = *(const float4*)(&At[kk][r0]);
            float4 b4 = *(const float4*)(&Bs[kk][c0]);
            float aa[4] = {a4.x, a4.y, a4.z, a4.w};
            float bb[4] = {b4.x, b4.y, b4.z, b4.w};
            #pragma unroll
            for (int i = 0; i < 4; ++i)
                #pragma unroll
                for (int j = 0; j < 4; ++j)
                    acc[i][j] = fmaf(aa[i], bb[j], acc[i][j]);
        }
        __syncthreads();
    }
    const float4 b4 = *(const float4*)(bias + cb * 64 + c0);
    #pragma unroll
    for (int i = 0; i < 4; ++i) {
        const int t = rb * 64 + r0 + i;
        float4 o;
        o.x = acc[i][0] + b4.x;
        o.y = acc[i][1] + b4.y;
        o.z = acc[i][2] + b4.z;
        o.w = acc[i][3] + b4.w;
        *(float4*)(out + (size_t)t * DM + cb * 64 + c0) = o;
    }
}

// ---------------------------------------------------------------------------
extern "C" void kernel_launch(void* const* d_in, const int* in_sizes, int n_in,
                              void* d_out, int out_size, void* d_ws, size_t ws_size,
                              hipStream_t stream) {
    const float* x      = (const float*)d_in[0];
    const float* w_qkv  = (const float*)d_in[1];
    const float* w_proj = (const float*)d_in[2];
    const float* b_proj = (const float*)d_in[3];
    float* out = (float*)d_out;
    float* ws  = (float*)d_ws;

    const size_t HS = (size_t)NH * T_SEQ * DH;  // 3,145,728 floats per tensor
    float* q   = ws;
    float* k   = ws + HS;
    float* v   = ws + 2 * HS;
    float* att = ws + 3 * HS;   // [t][h*64+d] = [4096][768]

    qkv_gemm_kernel<<<dim3(36, 64), 256, 0, stream>>>(x, w_qkv, q, k, v);
    attn_kernel<<<dim3(64, NH), 256, 0, stream>>>(q, k, v, att);
    proj_gemm_kernel<<<dim3(12, 64), 256, 0, stream>>>(att, w_proj, b_proj, out);
}

// Round 2
// 411.620 us; speedup vs baseline: 2.6939x; 2.6939x over previous
//
#include <hip/hip_runtime.h>

#define T_SEQ 4096
#define DM    768
#define NH    12
#define DH    64
#define NC    2304   // 3 * DM

using half8  = __attribute__((ext_vector_type(8))) _Float16;
using half4v = __attribute__((ext_vector_type(4))) _Float16;
using f32x4  = __attribute__((ext_vector_type(4))) float;

// ---------------------------------------------------------------------------
// Kernel 1: H = X @ W_qkv (fp32 compute), outputs fp16 Q/K/V in [h][t][64].
// Q pre-scaled by (1/sqrt(64)) * log2(e) so attention can use exp2 throughout.
// ---------------------------------------------------------------------------
__global__ __launch_bounds__(256)
void qkv_gemm_kernel(const float* __restrict__ x, const float* __restrict__ w,
                     _Float16* __restrict__ q, _Float16* __restrict__ k,
                     _Float16* __restrict__ v) {
    __shared__ float At[16][68];   // [kk][row] transposed, padded
    __shared__ float Bs[16][64];   // [kk][col]
    const int tid = threadIdx.x;
    const int cb = blockIdx.x;     // 0..35
    const int rb = blockIdx.y;     // 0..63
    const int r0 = (tid >> 4) * 4;
    const int c0 = (tid & 15) * 4;
    const int arow = tid >> 2;         // 0..63
    const int ak4  = (tid & 3) * 4;    // 0,4,8,12
    const int bkk  = tid >> 4;         // 0..15
    const int bc4  = (tid & 15) * 4;

    const int head  = cb / 3;
    const int which = cb % 3;
    _Float16* dst = (which == 0) ? q : (which == 1) ? k : v;
    // Q: 1/8 * log2(e) folded in; K,V: 1.0
    const float wscale = (which == 0) ? 0.18033688011112042f : 1.0f;

    float acc[4][4] = {};
    for (int kt = 0; kt < DM / 16; ++kt) {
        float4 av = *(const float4*)(x + (size_t)(rb * 64 + arow) * DM + kt * 16 + ak4);
        float4 bv = *(const float4*)(w + (size_t)(kt * 16 + bkk) * NC + cb * 64 + bc4);
        At[ak4 + 0][arow] = av.x;
        At[ak4 + 1][arow] = av.y;
        At[ak4 + 2][arow] = av.z;
        At[ak4 + 3][arow] = av.w;
        *(float4*)(&Bs[bkk][bc4]) = bv;
        __syncthreads();
        #pragma unroll
        for (int kk = 0; kk < 16; ++kk) {
            float4 a4 = *(const float4*)(&At[kk][r0]);
            float4 b4 = *(const float4*)(&Bs[kk][c0]);
            float aa[4] = {a4.x, a4.y, a4.z, a4.w};
            float bb[4] = {b4.x, b4.y, b4.z, b4.w};
            #pragma unroll
            for (int i = 0; i < 4; ++i)
                #pragma unroll
                for (int j = 0; j < 4; ++j)
                    acc[i][j] = fmaf(aa[i], bb[j], acc[i][j]);
        }
        __syncthreads();
    }
    #pragma unroll
    for (int i = 0; i < 4; ++i) {
        const int t = rb * 64 + r0 + i;
        half4v o = { (_Float16)(acc[i][0] * wscale), (_Float16)(acc[i][1] * wscale),
                     (_Float16)(acc[i][2] * wscale), (_Float16)(acc[i][3] * wscale) };
        *(half4v*)(dst + (size_t)(head * T_SEQ + t) * DH + c0) = o;
    }
}

// ---------------------------------------------------------------------------
// Kernel 2: V [h][t][d] -> Vt [h][d][t] (fp16). 64x64 LDS tile, pad 65 so the
// scalar column reads are ~2-way. Tiny kernel (~19 MB total traffic).
// ---------------------------------------------------------------------------
__global__ __launch_bounds__(256)
void vt_kernel(const _Float16* __restrict__ v, _Float16* __restrict__ vt) {
    __shared__ _Float16 tile[64][65];
    const int tid = threadIdx.x;
    const int tb = blockIdx.x, h = blockIdx.y;
    const int r = tid >> 2, c0 = (tid & 3) * 16;
    const _Float16* src = v + ((size_t)h * T_SEQ + tb * 64 + r) * 64 + c0;
    half8 a0 = *(const half8*)(src);
    half8 a1 = *(const half8*)(src + 8);
    #pragma unroll
    for (int j = 0; j < 8; ++j) tile[r][c0 + j] = a0[j];
    #pragma unroll
    for (int j = 0; j < 8; ++j) tile[r][c0 + 8 + j] = a1[j];
    __syncthreads();
    const int d = tid >> 2, t0 = (tid & 3) * 16;
    half8 o0, o1;
    #pragma unroll
    for (int j = 0; j < 8; ++j) o0[j] = tile[t0 + j][d];
    #pragma unroll
    for (int j = 0; j < 8; ++j) o1[j] = tile[t0 + 8 + j][d];
    _Float16* dst = vt + ((size_t)h * 64 + d) * T_SEQ + tb * 64 + t0;
    *(half8*)(dst) = o0;
    *(half8*)(dst + 8) = o1;
}

// ---------------------------------------------------------------------------
// Kernel 3: flash attention with fp16 MFMA (16x16x32).
// Block = (head, 64 q-rows), 4 waves x 16 rows. KVBLK = 64.
// K LDS [kv][d], Vt LDS [d][kv], both XOR-swizzled (granule ^= row&7) so all
// 16B fragment reads are <=2-way bank aliased. P goes through a per-wave
// swizzled LDS buffer to re-layout C/D -> A-frag. exp2-domain softmax
// (log2e folded into Q). Next tile prefetched into regs during compute (T14).
// Fragment layouts (mfma_f32_16x16x32_f16):
//   A: row = lane&15, k = (lane>>4)*8 + j   (16B contiguous per lane)
//   B: col = lane&15, k = (lane>>4)*8 + j
//   C/D: col = lane&15, row = (lane>>4)*4 + reg   [m89-verified]
// ---------------------------------------------------------------------------
__global__ __launch_bounds__(256, 4)
void attn_mfma_kernel(const _Float16* __restrict__ qg,
                      const _Float16* __restrict__ kg,
                      const _Float16* __restrict__ vtg,
                      float* __restrict__ att) {
    __shared__ _Float16 Klds[4096];      // 8 KB, swizzled [kv][d]
    __shared__ _Float16 Vlds[4096];      // 8 KB, swizzled [d][kv]
    __shared__ _Float16 Plds[4][1024];   // 8 KB, per-wave swizzled [q][kv]

    const int tid  = threadIdx.x;
    const int lane = tid & 63;
    const int w    = tid >> 6;
    const int lrow = lane >> 4;   // 0..3
    const int lcol = lane & 15;

    // XCD-aware swizzle: 768 blocks = 8 XCDs x 96; each XCD sees ~2 heads.
    const int bid  = blockIdx.x;
    const int virt = (bid & 7) * 96 + (bid >> 3);
    const int h    = virt >> 6;
    const int qb   = 63 - (virt & 63);   // heavy q-blocks first

    // Q fragments (A operand), scale already folded in at QKV.
    const int qrow = qb * 64 + w * 16 + lcol;
    const _Float16* Qp = qg + ((size_t)h * T_SEQ + qrow) * DH + lrow * 8;
    const half8 qf0 = *(const half8*)(Qp);
    const half8 qf1 = *(const half8*)(Qp + 32);

    f32x4 oacc[4];
    #pragma unroll
    for (int tc = 0; tc < 4; ++tc) oacc[tc] = (f32x4){0.f, 0.f, 0.f, 0.f};
    float m_r[4], l_r[4];
    #pragma unroll
    for (int r = 0; r < 4; ++r) { m_r[r] = -1e30f; l_r[r] = 0.f; }

    const _Float16* Kh = kg  + (size_t)h * T_SEQ * DH;
    const _Float16* Vh = vtg + (size_t)h * DH * T_SEQ;

    // staging granules: 512 x 16B per tile, 2 per thread
    const int g0 = tid, g1 = tid + 256;
    const int g0r = g0 >> 3, g0c = g0 & 7, g1r = g1 >> 3, g1c = g1 & 7;
    const int swb0 = g0r * 128 + ((g0c ^ (g0r & 7)) << 4);
    const int swb1 = g1r * 128 + ((g1c ^ (g1r & 7)) << 4);

    // prologue prefetch: tile 0 -> regs
    half8 kr0 = *(const half8*)(Kh + (size_t)g0r * DH + g0c * 8);
    half8 kr1 = *(const half8*)(Kh + (size_t)g1r * DH + g1c * 8);
    half8 vr0 = *(const half8*)(Vh + (size_t)g0r * T_SEQ + g0c * 8);
    half8 vr1 = *(const half8*)(Vh + (size_t)g1r * T_SEQ + g1c * 8);

    for (int kb = 0; kb <= qb; ++kb) {
        __syncthreads();   // previous tile's PV reads complete
        *(half8*)((char*)Klds + swb0) = kr0;
        *(half8*)((char*)Klds + swb1) = kr1;
        *(half8*)((char*)Vlds + swb0) = vr0;
        *(half8*)((char*)Vlds + swb1) = vr1;
        __syncthreads();   // staged tile visible

        // T14: issue next tile's global loads; latency hides under compute
        if (kb < qb) {
            const _Float16* Kn = Kh + (size_t)(kb + 1) * 64 * DH;
            const _Float16* Vn = Vh + (kb + 1) * 64;
            kr0 = *(const half8*)(Kn + (size_t)g0r * DH + g0c * 8);
            kr1 = *(const half8*)(Kn + (size_t)g1r * DH + g1c * 8);
            vr0 = *(const half8*)(Vn + (size_t)g0r * T_SEQ + g0c * 8);
            vr1 = *(const half8*)(Vn + (size_t)g1r * T_SEQ + g1c * 8);
        }

        // ---- S = Q K^T  (16 q-rows x 64 kv per wave)
        f32x4 s[4];
        #pragma unroll
        for (int tc = 0; tc < 4; ++tc) {
            const int kvr = tc * 16 + lcol;
            const int b0 = kvr * 128 + ((lrow       ^ (kvr & 7)) << 4);
            const int b1 = kvr * 128 + (((4 + lrow) ^ (kvr & 7)) << 4);
            half8 kf0 = *(const half8*)((const char*)Klds + b0);
            half8 kf1 = *(const half8*)((const char*)Klds + b1);
            f32x4 a = (f32x4){0.f, 0.f, 0.f, 0.f};
            a = __builtin_amdgcn_mfma_f32_16x16x32_f16(qf0, kf0, a, 0, 0, 0);
            a = __builtin_amdgcn_mfma_f32_16x16x32_f16(qf1, kf1, a, 0, 0, 0);
            s[tc] = a;
        }

        // ---- causal mask (diagonal tile only)
        if (kb == qb) {
            const int rbase = w * 16 + lrow * 4;
            #pragma unroll
            for (int tc = 0; tc < 4; ++tc) {
                const int col = tc * 16 + lcol;
                #pragma unroll
                for (int r = 0; r < 4; ++r)
                    if (col > rbase + r) s[tc][r] = -1e30f;
            }
        }

        // ---- online softmax (exp2 domain), wave-parallel row reduce
        float mx[4];
        #pragma unroll
        for (int r = 0; r < 4; ++r)
            mx[r] = fmaxf(fmaxf(s[0][r], s[1][r]), fmaxf(s[2][r], s[3][r]));
        #pragma unroll
        for (int r = 0; r < 4; ++r) {
            mx[r] = fmaxf(mx[r], __shfl_xor(mx[r], 1));
            mx[r] = fmaxf(mx[r], __shfl_xor(mx[r], 2));
            mx[r] = fmaxf(mx[r], __shfl_xor(mx[r], 4));
            mx[r] = fmaxf(mx[r], __shfl_xor(mx[r], 8));
        }
        float alpha[4], rsum[4];
        #pragma unroll
        for (int r = 0; r < 4; ++r) {
            const float mnew = fmaxf(m_r[r], mx[r]);
            alpha[r] = exp2f(m_r[r] - mnew);
            m_r[r] = mnew;
            rsum[r] = 0.f;
        }
        #pragma unroll
        for (int tc = 0; tc < 4; ++tc)
            #pragma unroll
            for (int r = 0; r < 4; ++r) {
                const float p = exp2f(s[tc][r] - m_r[r]);
                s[tc][r] = p;
                rsum[r] += p;
            }
        #pragma unroll
        for (int r = 0; r < 4; ++r) {
            rsum[r] += __shfl_xor(rsum[r], 1);
            rsum[r] += __shfl_xor(rsum[r], 2);
            rsum[r] += __shfl_xor(rsum[r], 4);
            rsum[r] += __shfl_xor(rsum[r], 8);
            l_r[r] = l_r[r] * alpha[r] + rsum[r];
        }
        #pragma unroll
        for (int tc = 0; tc < 4; ++tc)
            #pragma unroll
            for (int r = 0; r < 4; ++r)
                oacc[tc][r] *= alpha[r];

        // ---- P (fp16) -> this wave's Plds region, swizzled; same-wave only
        char* pw = (char*)Plds[w];
        #pragma unroll
        for (int tc = 0; tc < 4; ++tc) {
            const int colg = tc * 2 + (lcol >> 3);      // 16B-granule of col
            #pragma unroll
            for (int r = 0; r < 4; ++r) {
                const int row = lrow * 4 + r;
                const int byte = row * 128 + ((colg ^ (row & 7)) << 4) + (lane & 7) * 2;
                *(_Float16*)(pw + byte) = (_Float16)s[tc][r];
            }
        }
        asm volatile("s_waitcnt lgkmcnt(0)" ::: "memory");
        __builtin_amdgcn_sched_barrier(0);

        // ---- P fragments (A operand)
        const int prow = lcol;
        const int pb0 = prow * 128 + ((lrow       ^ (prow & 7)) << 4);
        const int pb1 = prow * 128 + (((4 + lrow) ^ (prow & 7)) << 4);
        const half8 pf0 = *(const half8*)((const char*)pw + pb0);
        const half8 pf1 = *(const half8*)((const char*)pw + pb1);

        // ---- PV
        #pragma unroll
        for (int tc = 0; tc < 4; ++tc) {
            const int dr = tc * 16 + lcol;
            const int b0 = dr * 128 + ((lrow       ^ (dr & 7)) << 4);
            const int b1 = dr * 128 + (((4 + lrow) ^ (dr & 7)) << 4);
            half8 vf0 = *(const half8*)((const char*)Vlds + b0);
            half8 vf1 = *(const half8*)((const char*)Vlds + b1);
            oacc[tc] = __builtin_amdgcn_mfma_f32_16x16x32_f16(pf0, vf0, oacc[tc], 0, 0, 0);
            oacc[tc] = __builtin_amdgcn_mfma_f32_16x16x32_f16(pf1, vf1, oacc[tc], 0, 0, 0);
        }
    }

    // ---- epilogue: normalize, write att [t][h*64+d] (fp32)
    #pragma unroll
    for (int r = 0; r < 4; ++r) {
        const float inv = 1.0f / l_r[r];
        const int qq = qb * 64 + w * 16 + lrow * 4 + r;
        #pragma unroll
        for (int tc = 0; tc < 4; ++tc)
            att[(size_t)qq * DM + h * DH + tc * 16 + lcol] = oacc[tc][r] * inv;
    }
}

// ---------------------------------------------------------------------------
// Kernel 4: out = att @ W_proj + b  (fp32, unchanged)
// ---------------------------------------------------------------------------
__global__ __launch_bounds__(256)
void proj_gemm_kernel(const float* __restrict__ a, const float* __restrict__ w,
                      const float* __restrict__ bias, float* __restrict__ out) {
    __shared__ float At[16][68];
    __shared__ float Bs[16][64];
    const int tid = threadIdx.x;
    const int cb = blockIdx.x;     // 0..11
    const int rb = blockIdx.y;     // 0..63
    const int r0 = (tid >> 4) * 4;
    const int c0 = (tid & 15) * 4;
    const int arow = tid >> 2;
    const int ak4  = (tid & 3) * 4;
    const int bkk  = tid >> 4;
    const int bc4  = (tid & 15) * 4;

    float acc[4][4] = {};
    for (int kt = 0; kt < DM / 16; ++kt) {
        float4 av = *(const float4*)(a + (size_t)(rb * 64 + arow) * DM + kt * 16 + ak4);
        float4 bv = *(const float4*)(w + (size_t)(kt * 16 + bkk) * DM + cb * 64 + bc4);
        At[ak4 + 0][arow] = av.x;
        At[ak4 + 1][arow] = av.y;
        At[ak4 + 2][arow] = av.z;
        At[ak4 + 3][arow] = av.w;
        *(float4*)(&Bs[bkk][bc4]) = bv;
        __syncthreads();
        #pragma unroll
        for (int kk = 0; kk < 16; ++kk) {
            float4 a4 = *(const float4*)(&At[kk][r0]);
            float4 b4 = *(const float4*)(&Bs[kk][c0]);
            float aa[4] = {a4.x, a4.y, a4.z, a4.w};
            float bb[4] = {b4.x, b4.y, b4.z, b4.w};
            #pragma unroll
            for (int i = 0; i < 4; ++i)
                #pragma unroll
                for (int j = 0; j < 4; ++j)
                    acc[i][j] = fmaf(aa[i], bb[j], acc[i][j]);
        }
        __syncthreads();
    }
    const float4 b4 = *(const float4*)(bias + cb * 64 + c0);
    #pragma unroll
    for (int i = 0; i < 4; ++i) {
        const int t = rb * 64 + r0 + i;
        float4 o;
        o.x = acc[i][0] + b4.x;
        o.y = acc[i][1] + b4.y;
        o.z = acc[i][2] + b4.z;
        o.w = acc[i][3] + b4.w;
        *(float4*)(out + (size_t)t * DM + cb * 64 + c0) = o;
    }
}

// ---------------------------------------------------------------------------
extern "C" void kernel_launch(void* const* d_in, const int* in_sizes, int n_in,
                              void* d_out, int out_size, void* d_ws, size_t ws_size,
                              hipStream_t stream) {
    const float* x      = (const float*)d_in[0];
    const float* w_qkv  = (const float*)d_in[1];
    const float* w_proj = (const float*)d_in[2];
    const float* b_proj = (const float*)d_in[3];
    float* out = (float*)d_out;

    char* wsb = (char*)d_ws;
    const size_t HSZ = (size_t)NH * T_SEQ * DH * sizeof(_Float16);  // 6 MB
    _Float16* q  = (_Float16*)(wsb);
    _Float16* k  = (_Float16*)(wsb + HSZ);
    _Float16* v  = (_Float16*)(wsb + 2 * HSZ);
    _Float16* vt = (_Float16*)(wsb + 3 * HSZ);
    float*   att = (float*)(wsb + 4 * HSZ);      // [4096][768] fp32

    qkv_gemm_kernel<<<dim3(36, 64), 256, 0, stream>>>(x, w_qkv, q, k, v);
    vt_kernel<<<dim3(64, NH), 256, 0, stream>>>(v, vt);
    attn_mfma_kernel<<<dim3(768), 256, 0, stream>>>(q, k, vt, att);
    proj_gemm_kernel<<<dim3(12, 64), 256, 0, stream>>>(att, w_proj, b_proj, out);
}

// Round 3
// 201.290 us; speedup vs baseline: 5.5089x; 2.0449x over previous
//
#include <hip/hip_runtime.h>

#define T_SEQ 4096
#define DM    768
#define NH    12
#define DH    64
#define NC    2304   // 3 * DM

using half8 = __attribute__((ext_vector_type(8))) _Float16;
using f32x4 = __attribute__((ext_vector_type(4))) float;
typedef unsigned int u32;

__device__ __forceinline__ void async_copy16(void* lds, const void* g) {
    __builtin_amdgcn_global_load_lds(
        (const __attribute__((address_space(1))) u32*)g,
        (__attribute__((address_space(3))) u32*)lds, 16, 0, 0);
}

// ---------------------------------------------------------------------------
// x (fp32) -> xh (fp16), 8 elems/thread
// ---------------------------------------------------------------------------
__global__ __launch_bounds__(256)
void convert_x_kernel(const float* __restrict__ x, _Float16* __restrict__ xh) {
    const size_t i = ((size_t)blockIdx.x * 256 + threadIdx.x) * 8;
    float4 a = *(const float4*)(x + i);
    float4 b = *(const float4*)(x + i + 4);
    half8 o = { (_Float16)a.x, (_Float16)a.y, (_Float16)a.z, (_Float16)a.w,
                (_Float16)b.x, (_Float16)b.y, (_Float16)b.z, (_Float16)b.w };
    *(half8*)(xh + i) = o;
}

// ---------------------------------------------------------------------------
// src [R][C] fp32 -> dst [C][R] fp16 (weight transpose+convert), 64x64 tiles
// ---------------------------------------------------------------------------
__global__ __launch_bounds__(256)
void transpose_convert_kernel(const float* __restrict__ src,
                              _Float16* __restrict__ dst, int R, int C) {
    __shared__ _Float16 tile[64][72];
    const int tid = threadIdx.x;
    const int tc0 = blockIdx.x * 64;   // C-dim origin
    const int tr0 = blockIdx.y * 64;   // R-dim origin
    const int r = tid >> 2, c4 = (tid & 3) * 16;
    const float* sp = src + (size_t)(tr0 + r) * C + tc0 + c4;
    #pragma unroll
    for (int j = 0; j < 16; j += 4) {
        float4 t4 = *(const float4*)(sp + j);
        tile[r][c4 + j + 0] = (_Float16)t4.x;
        tile[r][c4 + j + 1] = (_Float16)t4.y;
        tile[r][c4 + j + 2] = (_Float16)t4.z;
        tile[r][c4 + j + 3] = (_Float16)t4.w;
    }
    __syncthreads();
    const int c = tid >> 2, r4 = (tid & 3) * 16;
    half8 o0, o1;
    #pragma unroll
    for (int j = 0; j < 8; ++j) o0[j] = tile[r4 + j][c];
    #pragma unroll
    for (int j = 0; j < 8; ++j) o1[j] = tile[r4 + 8 + j][c];
    _Float16* dp = dst + (size_t)(tc0 + c) * R + tr0 + r4;
    *(half8*)(dp) = o0;
    *(half8*)(dp + 8) = o1;
}

// ---------------------------------------------------------------------------
// fp16 MFMA GEMM core (m97 structure): C(M,N) = A(M,K) @ Bt(N,K)^T
// 128x128 tile, BK=64, 4 waves (2x2), each wave 64x64 = 4x4 frags 16x16x32.
// LDS [row][64] fp16, 128B/row = 8 granules; swizzle g ^= row&7 on BOTH the
// staging source (inverse-permuted global addr, linear LDS dest — m104 rule)
// and the ds_read_b128 fragment address -> conflict-free.
// ---------------------------------------------------------------------------
__global__ __launch_bounds__(256, 2)
void qkv_mfma_kernel(const _Float16* __restrict__ A,    // xh [4096][768]
                     const _Float16* __restrict__ Bt,   // wqkvT [2304][768]
                     _Float16* __restrict__ q, _Float16* __restrict__ k,
                     _Float16* __restrict__ v) {
    __shared__ _Float16 Alds[128 * 64];   // 16 KB
    __shared__ _Float16 Blds[128 * 64];   // 16 KB
    const int tid  = threadIdx.x;
    const int lane = tid & 63;
    const int w    = tid >> 6;
    const int wr = w >> 1, wc = w & 1;
    const int lrow = lane >> 4, lcol = lane & 15;

    const int bid  = blockIdx.x;                    // 576 = 8 * 72
    const int virt = (bid & 7) * 72 + (bid >> 3);
    const int cbn  = virt % 18, rbn = virt / 18;

    const _Float16* Ag = A  + (size_t)rbn * 128 * DM;
    const _Float16* Bg = Bt + (size_t)cbn * 128 * DM;

    int srow[4], scol[4];
    #pragma unroll
    for (int i = 0; i < 4; ++i) {
        const int idx = i * 256 + tid;              // granule 0..1023
        srow[i] = idx >> 3;
        scol[i] = ((idx & 7) ^ (srow[i] & 7)) * 8;  // inverse-swizzled k-offset
    }

    f32x4 acc[4][4];
    #pragma unroll
    for (int mf = 0; mf < 4; ++mf)
        #pragma unroll
        for (int nf = 0; nf < 4; ++nf) acc[mf][nf] = (f32x4){0.f, 0.f, 0.f, 0.f};

    for (int kt = 0; kt < DM / 64; ++kt) {
        const int k0 = kt * 64;
        __syncthreads();
        #pragma unroll
        for (int i = 0; i < 4; ++i) {
            async_copy16((char*)Alds + (i * 256 + w * 64) * 16,
                         Ag + (size_t)srow[i] * DM + k0 + scol[i]);
            async_copy16((char*)Blds + (i * 256 + w * 64) * 16,
                         Bg + (size_t)srow[i] * DM + k0 + scol[i]);
        }
        __syncthreads();
        #pragma unroll
        for (int kh = 0; kh < 2; ++kh) {
            half8 af[4], bf[4];
            const int ag = kh * 4 + lrow;
            #pragma unroll
            for (int f = 0; f < 4; ++f) {
                const int ar = wr * 64 + f * 16 + lcol;
                af[f] = *(const half8*)((const char*)Alds +
                          ar * 128 + ((ag ^ (ar & 7)) << 4));
                const int br = wc * 64 + f * 16 + lcol;
                bf[f] = *(const half8*)((const char*)Blds +
                          br * 128 + ((ag ^ (br & 7)) << 4));
            }
            #pragma unroll
            for (int mf = 0; mf < 4; ++mf)
                #pragma unroll
                for (int nf = 0; nf < 4; ++nf)
                    acc[mf][nf] = __builtin_amdgcn_mfma_f32_16x16x32_f16(
                        af[mf], bf[nf], acc[mf][nf], 0, 0, 0);
        }
    }

    // epilogue: scatter to q/k/v [h][t][64] fp16; Q pre-scaled 0.125*log2(e)
    #pragma unroll
    for (int nf = 0; nf < 4; ++nf) {
        const int n = cbn * 128 + wc * 64 + nf * 16 + lcol;
        const int head  = n / 192;
        const int which = (n >> 6) % 3;
        const int d = n & 63;
        _Float16* dst = (which == 0) ? q : (which == 1) ? k : v;
        const float sc = (which == 0) ? 0.18033688011112042f : 1.0f;
        dst += (size_t)head * T_SEQ * DH + d;
        #pragma unroll
        for (int mf = 0; mf < 4; ++mf) {
            const int t0 = rbn * 128 + wr * 64 + mf * 16 + lrow * 4;
            #pragma unroll
            for (int r = 0; r < 4; ++r)
                dst[(size_t)(t0 + r) * DH] = (_Float16)(acc[mf][nf][r] * sc);
        }
    }
}

__global__ __launch_bounds__(256, 2)
void proj_mfma_kernel(const _Float16* __restrict__ A,    // att [4096][768] fp16
                      const _Float16* __restrict__ Bt,   // wprojT [768][768]
                      const float* __restrict__ bias, float* __restrict__ out) {
    __shared__ _Float16 Alds[128 * 64];
    __shared__ _Float16 Blds[128 * 64];
    const int tid  = threadIdx.x;
    const int lane = tid & 63;
    const int w    = tid >> 6;
    const int wr = w >> 1, wc = w & 1;
    const int lrow = lane >> 4, lcol = lane & 15;

    const int bid  = blockIdx.x;                    // 192 = 8 * 24
    const int virt = (bid & 7) * 24 + (bid >> 3);
    const int cbn  = virt % 6, rbn = virt / 6;

    const _Float16* Ag = A  + (size_t)rbn * 128 * DM;
    const _Float16* Bg = Bt + (size_t)cbn * 128 * DM;

    int srow[4], scol[4];
    #pragma unroll
    for (int i = 0; i < 4; ++i) {
        const int idx = i * 256 + tid;
        srow[i] = idx >> 3;
        scol[i] = ((idx & 7) ^ (srow[i] & 7)) * 8;
    }

    f32x4 acc[4][4];
    #pragma unroll
    for (int mf = 0; mf < 4; ++mf)
        #pragma unroll
        for (int nf = 0; nf < 4; ++nf) acc[mf][nf] = (f32x4){0.f, 0.f, 0.f, 0.f};

    for (int kt = 0; kt < DM / 64; ++kt) {
        const int k0 = kt * 64;
        __syncthreads();
        #pragma unroll
        for (int i = 0; i < 4; ++i) {
            async_copy16((char*)Alds + (i * 256 + w * 64) * 16,
                         Ag + (size_t)srow[i] * DM + k0 + scol[i]);
            async_copy16((char*)Blds + (i * 256 + w * 64) * 16,
                         Bg + (size_t)srow[i] * DM + k0 + scol[i]);
        }
        __syncthreads();
        #pragma unroll
        for (int kh = 0; kh < 2; ++kh) {
            half8 af[4], bf[4];
            const int ag = kh * 4 + lrow;
            #pragma unroll
            for (int f = 0; f < 4; ++f) {
                const int ar = wr * 64 + f * 16 + lcol;
                af[f] = *(const half8*)((const char*)Alds +
                          ar * 128 + ((ag ^ (ar & 7)) << 4));
                const int br = wc * 64 + f * 16 + lcol;
                bf[f] = *(const half8*)((const char*)Blds +
                          br * 128 + ((ag ^ (br & 7)) << 4));
            }
            #pragma unroll
            for (int mf = 0; mf < 4; ++mf)
                #pragma unroll
                for (int nf = 0; nf < 4; ++nf)
                    acc[mf][nf] = __builtin_amdgcn_mfma_f32_16x16x32_f16(
                        af[mf], bf[nf], acc[mf][nf], 0, 0, 0);
        }
    }

    #pragma unroll
    for (int nf = 0; nf < 4; ++nf) {
        const int n = cbn * 128 + wc * 64 + nf * 16 + lcol;
        const float b = bias[n];
        #pragma unroll
        for (int mf = 0; mf < 4; ++mf) {
            const int t0 = rbn * 128 + wr * 64 + mf * 16 + lrow * 4;
            #pragma unroll
            for (int r = 0; r < 4; ++r)
                out[(size_t)(t0 + r) * DM + n] = acc[mf][nf][r] + b;
        }
    }
}

// ---------------------------------------------------------------------------
// V [h][t][d] -> Vt [h][d][t] (fp16)
// ---------------------------------------------------------------------------
__global__ __launch_bounds__(256)
void vt_kernel(const _Float16* __restrict__ v, _Float16* __restrict__ vt) {
    __shared__ _Float16 tile[64][65];
    const int tid = threadIdx.x;
    const int tb = blockIdx.x, h = blockIdx.y;
    const int r = tid >> 2, c0 = (tid & 3) * 16;
    const _Float16* src = v + ((size_t)h * T_SEQ + tb * 64 + r) * 64 + c0;
    half8 a0 = *(const half8*)(src);
    half8 a1 = *(const half8*)(src + 8);
    #pragma unroll
    for (int j = 0; j < 8; ++j) tile[r][c0 + j] = a0[j];
    #pragma unroll
    for (int j = 0; j < 8; ++j) tile[r][c0 + 8 + j] = a1[j];
    __syncthreads();
    const int d = tid >> 2, t0 = (tid & 3) * 16;
    half8 o0, o1;
    #pragma unroll
    for (int j = 0; j < 8; ++j) o0[j] = tile[t0 + j][d];
    #pragma unroll
    for (int j = 0; j < 8; ++j) o1[j] = tile[t0 + 8 + j][d];
    _Float16* dst = vt + ((size_t)h * 64 + d) * T_SEQ + tb * 64 + t0;
    *(half8*)(dst) = o0;
    *(half8*)(dst + 8) = o1;
}

// ---------------------------------------------------------------------------
// Flash attention, fp16 MFMA 16x16x32 (unchanged from round 2 except fp16 out)
// ---------------------------------------------------------------------------
__global__ __launch_bounds__(256, 4)
void attn_mfma_kernel(const _Float16* __restrict__ qg,
                      const _Float16* __restrict__ kg,
                      const _Float16* __restrict__ vtg,
                      _Float16* __restrict__ att) {
    __shared__ _Float16 Klds[4096];
    __shared__ _Float16 Vlds[4096];
    __shared__ _Float16 Plds[4][1024];

    const int tid  = threadIdx.x;
    const int lane = tid & 63;
    const int w    = tid >> 6;
    const int lrow = lane >> 4;
    const int lcol = lane & 15;

    const int bid  = blockIdx.x;
    const int virt = (bid & 7) * 96 + (bid >> 3);
    const int h    = virt >> 6;
    const int qb   = 63 - (virt & 63);

    const int qrow = qb * 64 + w * 16 + lcol;
    const _Float16* Qp = qg + ((size_t)h * T_SEQ + qrow) * DH + lrow * 8;
    const half8 qf0 = *(const half8*)(Qp);
    const half8 qf1 = *(const half8*)(Qp + 32);

    f32x4 oacc[4];
    #pragma unroll
    for (int tc = 0; tc < 4; ++tc) oacc[tc] = (f32x4){0.f, 0.f, 0.f, 0.f};
    float m_r[4], l_r[4];
    #pragma unroll
    for (int r = 0; r < 4; ++r) { m_r[r] = -1e30f; l_r[r] = 0.f; }

    const _Float16* Kh = kg  + (size_t)h * T_SEQ * DH;
    const _Float16* Vh = vtg + (size_t)h * DH * T_SEQ;

    const int g0 = tid, g1 = tid + 256;
    const int g0r = g0 >> 3, g0c = g0 & 7, g1r = g1 >> 3, g1c = g1 & 7;
    const int swb0 = g0r * 128 + ((g0c ^ (g0r & 7)) << 4);
    const int swb1 = g1r * 128 + ((g1c ^ (g1r & 7)) << 4);

    half8 kr0 = *(const half8*)(Kh + (size_t)g0r * DH + g0c * 8);
    half8 kr1 = *(const half8*)(Kh + (size_t)g1r * DH + g1c * 8);
    half8 vr0 = *(const half8*)(Vh + (size_t)g0r * T_SEQ + g0c * 8);
    half8 vr1 = *(const half8*)(Vh + (size_t)g1r * T_SEQ + g1c * 8);

    for (int kb = 0; kb <= qb; ++kb) {
        __syncthreads();
        *(half8*)((char*)Klds + swb0) = kr0;
        *(half8*)((char*)Klds + swb1) = kr1;
        *(half8*)((char*)Vlds + swb0) = vr0;
        *(half8*)((char*)Vlds + swb1) = vr1;
        __syncthreads();

        if (kb < qb) {
            const _Float16* Kn = Kh + (size_t)(kb + 1) * 64 * DH;
            const _Float16* Vn = Vh + (kb + 1) * 64;
            kr0 = *(const half8*)(Kn + (size_t)g0r * DH + g0c * 8);
            kr1 = *(const half8*)(Kn + (size_t)g1r * DH + g1c * 8);
            vr0 = *(const half8*)(Vn + (size_t)g0r * T_SEQ + g0c * 8);
            vr1 = *(const half8*)(Vn + (size_t)g1r * T_SEQ + g1c * 8);
        }

        f32x4 s[4];
        #pragma unroll
        for (int tc = 0; tc < 4; ++tc) {
            const int kvr = tc * 16 + lcol;
            const int b0 = kvr * 128 + ((lrow       ^ (kvr & 7)) << 4);
            const int b1 = kvr * 128 + (((4 + lrow) ^ (kvr & 7)) << 4);
            half8 kf0 = *(const half8*)((const char*)Klds + b0);
            half8 kf1 = *(const half8*)((const char*)Klds + b1);
            f32x4 a = (f32x4){0.f, 0.f, 0.f, 0.f};
            a = __builtin_amdgcn_mfma_f32_16x16x32_f16(qf0, kf0, a, 0, 0, 0);
            a = __builtin_amdgcn_mfma_f32_16x16x32_f16(qf1, kf1, a, 0, 0, 0);
            s[tc] = a;
        }

        if (kb == qb) {
            const int rbase = w * 16 + lrow * 4;
            #pragma unroll
            for (int tc = 0; tc < 4; ++tc) {
                const int col = tc * 16 + lcol;
                #pragma unroll
                for (int r = 0; r < 4; ++r)
                    if (col > rbase + r) s[tc][r] = -1e30f;
            }
        }

        float mx[4];
        #pragma unroll
        for (int r = 0; r < 4; ++r)
            mx[r] = fmaxf(fmaxf(s[0][r], s[1][r]), fmaxf(s[2][r], s[3][r]));
        #pragma unroll
        for (int r = 0; r < 4; ++r) {
            mx[r] = fmaxf(mx[r], __shfl_xor(mx[r], 1));
            mx[r] = fmaxf(mx[r], __shfl_xor(mx[r], 2));
            mx[r] = fmaxf(mx[r], __shfl_xor(mx[r], 4));
            mx[r] = fmaxf(mx[r], __shfl_xor(mx[r], 8));
        }
        float alpha[4], rsum[4];
        #pragma unroll
        for (int r = 0; r < 4; ++r) {
            const float mnew = fmaxf(m_r[r], mx[r]);
            alpha[r] = exp2f(m_r[r] - mnew);
            m_r[r] = mnew;
            rsum[r] = 0.f;
        }
        #pragma unroll
        for (int tc = 0; tc < 4; ++tc)
            #pragma unroll
            for (int r = 0; r < 4; ++r) {
                const float p = exp2f(s[tc][r] - m_r[r]);
                s[tc][r] = p;
                rsum[r] += p;
            }
        #pragma unroll
        for (int r = 0; r < 4; ++r) {
            rsum[r] += __shfl_xor(rsum[r], 1);
            rsum[r] += __shfl_xor(rsum[r], 2);
            rsum[r] += __shfl_xor(rsum[r], 4);
            rsum[r] += __shfl_xor(rsum[r], 8);
            l_r[r] = l_r[r] * alpha[r] + rsum[r];
        }
        #pragma unroll
        for (int tc = 0; tc < 4; ++tc)
            #pragma unroll
            for (int r = 0; r < 4; ++r)
                oacc[tc][r] *= alpha[r];

        char* pw = (char*)Plds[w];
        #pragma unroll
        for (int tc = 0; tc < 4; ++tc) {
            const int colg = tc * 2 + (lcol >> 3);
            #pragma unroll
            for (int r = 0; r < 4; ++r) {
                const int row = lrow * 4 + r;
                const int byte = row * 128 + ((colg ^ (row & 7)) << 4) + (lane & 7) * 2;
                *(_Float16*)(pw + byte) = (_Float16)s[tc][r];
            }
        }
        asm volatile("s_waitcnt lgkmcnt(0)" ::: "memory");
        __builtin_amdgcn_sched_barrier(0);

        const int prow = lcol;
        const int pb0 = prow * 128 + ((lrow       ^ (prow & 7)) << 4);
        const int pb1 = prow * 128 + (((4 + lrow) ^ (prow & 7)) << 4);
        const half8 pf0 = *(const half8*)((const char*)pw + pb0);
        const half8 pf1 = *(const half8*)((const char*)pw + pb1);

        #pragma unroll
        for (int tc = 0; tc < 4; ++tc) {
            const int dr = tc * 16 + lcol;
            const int b0 = dr * 128 + ((lrow       ^ (dr & 7)) << 4);
            const int b1 = dr * 128 + (((4 + lrow) ^ (dr & 7)) << 4);
            half8 vf0 = *(const half8*)((const char*)Vlds + b0);
            half8 vf1 = *(const half8*)((const char*)Vlds + b1);
            oacc[tc] = __builtin_amdgcn_mfma_f32_16x16x32_f16(pf0, vf0, oacc[tc], 0, 0, 0);
            oacc[tc] = __builtin_amdgcn_mfma_f32_16x16x32_f16(pf1, vf1, oacc[tc], 0, 0, 0);
        }
    }

    #pragma unroll
    for (int r = 0; r < 4; ++r) {
        const float inv = 1.0f / l_r[r];
        const int qq = qb * 64 + w * 16 + lrow * 4 + r;
        #pragma unroll
        for (int tc = 0; tc < 4; ++tc)
            att[(size_t)qq * DM + h * DH + tc * 16 + lcol] =
                (_Float16)(oacc[tc][r] * inv);
    }
}

// ---------------------------------------------------------------------------
extern "C" void kernel_launch(void* const* d_in, const int* in_sizes, int n_in,
                              void* d_out, int out_size, void* d_ws, size_t ws_size,
                              hipStream_t stream) {
    const float* x      = (const float*)d_in[0];
    const float* w_qkv  = (const float*)d_in[1];
    const float* w_proj = (const float*)d_in[2];
    const float* b_proj = (const float*)d_in[3];
    float* out = (float*)d_out;

    _Float16* wsb = (_Float16*)d_ws;
    const size_t XS = (size_t)T_SEQ * DM;       // 3,145,728
    const size_t HS = (size_t)NH * T_SEQ * DH;  // 3,145,728
    _Float16* xh     = wsb;
    _Float16* wqkvT  = xh + XS;
    _Float16* wprojT = wqkvT + (size_t)NC * DM;
    _Float16* q      = wprojT + (size_t)DM * DM;
    _Float16* k      = q + HS;
    _Float16* v      = k + HS;
    _Float16* vt     = v + HS;
    _Float16* att    = vt + HS;                 // [4096][768] fp16

    convert_x_kernel<<<dim3(1536), 256, 0, stream>>>(x, xh);
    transpose_convert_kernel<<<dim3(36, 12), 256, 0, stream>>>(w_qkv, wqkvT, DM, NC);
    transpose_convert_kernel<<<dim3(12, 12), 256, 0, stream>>>(w_proj, wprojT, DM, DM);
    qkv_mfma_kernel<<<dim3(576), 256, 0, stream>>>(xh, wqkvT, q, k, v);
    vt_kernel<<<dim3(64, NH), 256, 0, stream>>>(v, vt);
    attn_mfma_kernel<<<dim3(768), 256, 0, stream>>>(q, k, vt, att);
    proj_mfma_kernel<<<dim3(192), 256, 0, stream>>>(att, wprojT, b_proj, out);
}

// Round 5
// 176.144 us; speedup vs baseline: 6.2953x; 1.1428x over previous
//
#include <hip/hip_runtime.h>

#define T_SEQ 4096
#define DM    768
#define NH    12
#define DH    64
#define NC    2304   // 3 * DM

using half8  = __attribute__((ext_vector_type(8))) _Float16;
using half4v = __attribute__((ext_vector_type(4))) _Float16;
using f32x4  = __attribute__((ext_vector_type(4))) float;
using f32x16 = __attribute__((ext_vector_type(16))) float;
typedef unsigned int u32;

union H8 { half8 v; u32 u[4]; };

// cvt_pkrtz returns __fp16 ext_vector(2); bit-cast straight to u32.
__device__ __forceinline__ u32 pkrtz_u32(float a, float b) {
    return __builtin_bit_cast(u32, __builtin_amdgcn_cvt_pkrtz(a, b));
}

__device__ __forceinline__ void async_copy16(void* lds, const void* g) {
    __builtin_amdgcn_global_load_lds(
        (const __attribute__((address_space(1))) u32*)g,
        (__attribute__((address_space(3))) u32*)lds, 16, 0, 0);
}

// ---------------------------------------------------------------------------
// x (fp32) -> xh (fp16)
// ---------------------------------------------------------------------------
__global__ __launch_bounds__(256)
void convert_x_kernel(const float* __restrict__ x, _Float16* __restrict__ xh) {
    const size_t i = ((size_t)blockIdx.x * 256 + threadIdx.x) * 8;
    float4 a = *(const float4*)(x + i);
    float4 b = *(const float4*)(x + i + 4);
    half8 o = { (_Float16)a.x, (_Float16)a.y, (_Float16)a.z, (_Float16)a.w,
                (_Float16)b.x, (_Float16)b.y, (_Float16)b.z, (_Float16)b.w };
    *(half8*)(xh + i) = o;
}

// ---------------------------------------------------------------------------
// src [R][C] fp32 -> dst [C][R] fp16 (weight transpose+convert)
// ---------------------------------------------------------------------------
__global__ __launch_bounds__(256)
void transpose_convert_kernel(const float* __restrict__ src,
                              _Float16* __restrict__ dst, int R, int C) {
    __shared__ _Float16 tile[64][72];
    const int tid = threadIdx.x;
    const int tc0 = blockIdx.x * 64;
    const int tr0 = blockIdx.y * 64;
    const int r = tid >> 2, c4 = (tid & 3) * 16;
    const float* sp = src + (size_t)(tr0 + r) * C + tc0 + c4;
    #pragma unroll
    for (int j = 0; j < 16; j += 4) {
        float4 t4 = *(const float4*)(sp + j);
        tile[r][c4 + j + 0] = (_Float16)t4.x;
        tile[r][c4 + j + 1] = (_Float16)t4.y;
        tile[r][c4 + j + 2] = (_Float16)t4.z;
        tile[r][c4 + j + 3] = (_Float16)t4.w;
    }
    __syncthreads();
    const int c = tid >> 2, r4 = (tid & 3) * 16;
    half8 o0, o1;
    #pragma unroll
    for (int j = 0; j < 8; ++j) o0[j] = tile[r4 + j][c];
    #pragma unroll
    for (int j = 0; j < 8; ++j) o1[j] = tile[r4 + 8 + j][c];
    _Float16* dp = dst + (size_t)(tc0 + c) * R + tr0 + r4;
    *(half8*)(dp) = o0;
    *(half8*)(dp + 8) = o1;
}

// ---------------------------------------------------------------------------
// fp16 MFMA GEMM (m97 structure)
// ---------------------------------------------------------------------------
__global__ __launch_bounds__(256, 2)
void qkv_mfma_kernel(const _Float16* __restrict__ A,
                     const _Float16* __restrict__ Bt,
                     _Float16* __restrict__ q, _Float16* __restrict__ k,
                     _Float16* __restrict__ v) {
    __shared__ _Float16 Alds[128 * 64];
    __shared__ _Float16 Blds[128 * 64];
    const int tid  = threadIdx.x;
    const int lane = tid & 63;
    const int w    = tid >> 6;
    const int wr = w >> 1, wc = w & 1;
    const int lrow = lane >> 4, lcol = lane & 15;

    const int bid  = blockIdx.x;                    // 576 = 8 * 72
    const int virt = (bid & 7) * 72 + (bid >> 3);
    const int cbn  = virt % 18, rbn = virt / 18;

    const _Float16* Ag = A  + (size_t)rbn * 128 * DM;
    const _Float16* Bg = Bt + (size_t)cbn * 128 * DM;

    int srow[4], scol[4];
    #pragma unroll
    for (int i = 0; i < 4; ++i) {
        const int idx = i * 256 + tid;
        srow[i] = idx >> 3;
        scol[i] = ((idx & 7) ^ (srow[i] & 7)) * 8;
    }

    f32x4 acc[4][4];
    #pragma unroll
    for (int mf = 0; mf < 4; ++mf)
        #pragma unroll
        for (int nf = 0; nf < 4; ++nf) acc[mf][nf] = (f32x4){0.f, 0.f, 0.f, 0.f};

    for (int kt = 0; kt < DM / 64; ++kt) {
        const int k0 = kt * 64;
        __syncthreads();
        #pragma unroll
        for (int i = 0; i < 4; ++i) {
            async_copy16((char*)Alds + (i * 256 + w * 64) * 16,
                         Ag + (size_t)srow[i] * DM + k0 + scol[i]);
            async_copy16((char*)Blds + (i * 256 + w * 64) * 16,
                         Bg + (size_t)srow[i] * DM + k0 + scol[i]);
        }
        __syncthreads();
        #pragma unroll
        for (int kh = 0; kh < 2; ++kh) {
            half8 af[4], bf[4];
            const int ag = kh * 4 + lrow;
            #pragma unroll
            for (int f = 0; f < 4; ++f) {
                const int ar = wr * 64 + f * 16 + lcol;
                af[f] = *(const half8*)((const char*)Alds +
                          ar * 128 + ((ag ^ (ar & 7)) << 4));
                const int br = wc * 64 + f * 16 + lcol;
                bf[f] = *(const half8*)((const char*)Blds +
                          br * 128 + ((ag ^ (br & 7)) << 4));
            }
            #pragma unroll
            for (int mf = 0; mf < 4; ++mf)
                #pragma unroll
                for (int nf = 0; nf < 4; ++nf)
                    acc[mf][nf] = __builtin_amdgcn_mfma_f32_16x16x32_f16(
                        af[mf], bf[nf], acc[mf][nf], 0, 0, 0);
        }
    }

    #pragma unroll
    for (int nf = 0; nf < 4; ++nf) {
        const int n = cbn * 128 + wc * 64 + nf * 16 + lcol;
        const int head  = n / 192;
        const int which = (n >> 6) % 3;
        const int d = n & 63;
        _Float16* dst = (which == 0) ? q : (which == 1) ? k : v;
        const float sc = (which == 0) ? 0.18033688011112042f : 1.0f;
        dst += (size_t)head * T_SEQ * DH + d;
        #pragma unroll
        for (int mf = 0; mf < 4; ++mf) {
            const int t0 = rbn * 128 + wr * 64 + mf * 16 + lrow * 4;
            #pragma unroll
            for (int r = 0; r < 4; ++r)
                dst[(size_t)(t0 + r) * DH] = (_Float16)(acc[mf][nf][r] * sc);
        }
    }
}

__global__ __launch_bounds__(256, 2)
void proj_mfma_kernel(const _Float16* __restrict__ A,
                      const _Float16* __restrict__ Bt,
                      const float* __restrict__ bias, float* __restrict__ out) {
    __shared__ _Float16 Alds[128 * 64];
    __shared__ _Float16 Blds[128 * 64];
    const int tid  = threadIdx.x;
    const int lane = tid & 63;
    const int w    = tid >> 6;
    const int wr = w >> 1, wc = w & 1;
    const int lrow = lane >> 4, lcol = lane & 15;

    const int bid  = blockIdx.x;                    // 192 = 8 * 24
    const int virt = (bid & 7) * 24 + (bid >> 3);
    const int cbn  = virt % 6, rbn = virt / 6;

    const _Float16* Ag = A  + (size_t)rbn * 128 * DM;
    const _Float16* Bg = Bt + (size_t)cbn * 128 * DM;

    int srow[4], scol[4];
    #pragma unroll
    for (int i = 0; i < 4; ++i) {
        const int idx = i * 256 + tid;
        srow[i] = idx >> 3;
        scol[i] = ((idx & 7) ^ (srow[i] & 7)) * 8;
    }

    f32x4 acc[4][4];
    #pragma unroll
    for (int mf = 0; mf < 4; ++mf)
        #pragma unroll
        for (int nf = 0; nf < 4; ++nf) acc[mf][nf] = (f32x4){0.f, 0.f, 0.f, 0.f};

    for (int kt = 0; kt < DM / 64; ++kt) {
        const int k0 = kt * 64;
        __syncthreads();
        #pragma unroll
        for (int i = 0; i < 4; ++i) {
            async_copy16((char*)Alds + (i * 256 + w * 64) * 16,
                         Ag + (size_t)srow[i] * DM + k0 + scol[i]);
            async_copy16((char*)Blds + (i * 256 + w * 64) * 16,
                         Bg + (size_t)srow[i] * DM + k0 + scol[i]);
        }
        __syncthreads();
        #pragma unroll
        for (int kh = 0; kh < 2; ++kh) {
            half8 af[4], bf[4];
            const int ag = kh * 4 + lrow;
            #pragma unroll
            for (int f = 0; f < 4; ++f) {
                const int ar = wr * 64 + f * 16 + lcol;
                af[f] = *(const half8*)((const char*)Alds +
                          ar * 128 + ((ag ^ (ar & 7)) << 4));
                const int br = wc * 64 + f * 16 + lcol;
                bf[f] = *(const half8*)((const char*)Blds +
                          br * 128 + ((ag ^ (br & 7)) << 4));
            }
            #pragma unroll
            for (int mf = 0; mf < 4; ++mf)
                #pragma unroll
                for (int nf = 0; nf < 4; ++nf)
                    acc[mf][nf] = __builtin_amdgcn_mfma_f32_16x16x32_f16(
                        af[mf], bf[nf], acc[mf][nf], 0, 0, 0);
        }
    }

    #pragma unroll
    for (int nf = 0; nf < 4; ++nf) {
        const int n = cbn * 128 + wc * 64 + nf * 16 + lcol;
        const float b = bias[n];
        #pragma unroll
        for (int mf = 0; mf < 4; ++mf) {
            const int t0 = rbn * 128 + wr * 64 + mf * 16 + lrow * 4;
            #pragma unroll
            for (int r = 0; r < 4; ++r)
                out[(size_t)(t0 + r) * DM + n] = acc[mf][nf][r] + b;
        }
    }
}

// ---------------------------------------------------------------------------
// V [h][t][d] -> Vt [h][d][t] (fp16)
// ---------------------------------------------------------------------------
__global__ __launch_bounds__(256)
void vt_kernel(const _Float16* __restrict__ v, _Float16* __restrict__ vt) {
    __shared__ _Float16 tile[64][65];
    const int tid = threadIdx.x;
    const int tb = blockIdx.x, h = blockIdx.y;
    const int r = tid >> 2, c0 = (tid & 3) * 16;
    const _Float16* src = v + ((size_t)h * T_SEQ + tb * 64 + r) * 64 + c0;
    half8 a0 = *(const half8*)(src);
    half8 a1 = *(const half8*)(src + 8);
    #pragma unroll
    for (int j = 0; j < 8; ++j) tile[r][c0 + j] = a0[j];
    #pragma unroll
    for (int j = 0; j < 8; ++j) tile[r][c0 + 8 + j] = a1[j];
    __syncthreads();
    const int d = tid >> 2, t0 = (tid & 3) * 16;
    half8 o0, o1;
    #pragma unroll
    for (int j = 0; j < 8; ++j) o0[j] = tile[t0 + j][d];
    #pragma unroll
    for (int j = 0; j < 8; ++j) o1[j] = tile[t0 + 8 + j][d];
    _Float16* dst = vt + ((size_t)h * 64 + d) * T_SEQ + tb * 64 + t0;
    *(half8*)(dst) = o0;
    *(half8*)(dst + 8) = o1;
}

// ---------------------------------------------------------------------------
// Flash attention, swapped-operand 32x32x16 MFMA, zero LDS / zero barriers.
// One wave = 32 q-rows (q = q0 + lane&31; each lane owns ONE row -> scalar
// m, l). Per 64-kv iteration:
//   S^T[kv][q] = mfma(A=K, B=Q) x2 tiles x4 d-slots.
//   C/D layout: col(lane&31)=q, row = (reg&3)+8*(reg>>2)+4*(lane>>5) = kv.
//   Softmax fully in-register: 31 in-lane max + 1 shfl_xor(32); defer-max
//   (T13, THR=11 log2-units) skips O-rescale when max didn't grow.
//   P -> PV B-frags: cvt_pkrtz pairs + shfl_xor(32) half-exchange (T12).
//   O^T[d][q] += mfma(A=V^T, B=P̂). V^T frags read straight from global vt.
// K/V read from global per-use: per-XCD set ~3 heads x 1MB fits 4MB L2.
// Grid: 1536 one-wave blocks, c = 127 - bid/12 (heavy-first, balanced).
// ---------------------------------------------------------------------------
__global__ __launch_bounds__(64)
void attn_mfma32_kernel(const _Float16* __restrict__ qg,
                        const _Float16* __restrict__ kg,
                        const _Float16* __restrict__ vtg,
                        _Float16* __restrict__ att) {
    const int lane = threadIdx.x & 63;
    const int l31  = lane & 31;
    const int hi   = lane >> 5;

    const int bid = blockIdx.x;
    const int h   = bid % NH;
    const int c   = 127 - bid / NH;      // q-chunk, heavy first
    const int q0  = c * 32;
    const int q   = q0 + l31;            // this lane's q-row
    const int niter = c / 2 + 1;

    const _Float16* Qh = qg  + ((size_t)h * T_SEQ + q) * DH;
    const _Float16* Kh = kg  + (size_t)h * T_SEQ * DH;
    const _Float16* Vh = vtg + (size_t)h * DH * T_SEQ;

    // Q fragments (B operand): col=lane&31=q, k(d) = 16*ks + hi*8 + j
    half8 qf[4];
    #pragma unroll
    for (int ks = 0; ks < 4; ++ks)
        qf[ks] = *(const half8*)(Qh + ks * 16 + hi * 8);

    f32x16 o0v = {}, o1v = {};           // O^T d-tiles 0..31, 32..63
    float m = -1e30f, l = 0.f;

    for (int it = 0; it < niter; ++it) {
        const int kvb = it * 64;

        // ---- K frags (A operand): row=lane&31=kv, k(d)=16ks+hi*8+j
        half8 kfA[4], kfB[4];
        #pragma unroll
        for (int ks = 0; ks < 4; ++ks) {
            kfA[ks] = *(const half8*)(Kh + (size_t)(kvb + l31) * DH + ks * 16 + hi * 8);
            kfB[ks] = *(const half8*)(Kh + (size_t)(kvb + 32 + l31) * DH + ks * 16 + hi * 8);
        }
        // ---- V^T frags early (A operand): row=lane&31=d, k(kv)=16ks2+hi*8+j
        half8 vf[2][2][2];   // [kv-tile][dt][ks2]
        #pragma unroll
        for (int t = 0; t < 2; ++t)
            #pragma unroll
            for (int dt = 0; dt < 2; ++dt)
                #pragma unroll
                for (int ks2 = 0; ks2 < 2; ++ks2)
                    vf[t][dt][ks2] = *(const half8*)(Vh +
                        (size_t)(dt * 32 + l31) * T_SEQ +
                        kvb + t * 32 + ks2 * 16 + hi * 8);

        // ---- S^T = K Q^T
        f32x16 sA = {}, sB = {};
        #pragma unroll
        for (int ks = 0; ks < 4; ++ks) {
            sA = __builtin_amdgcn_mfma_f32_32x32x16_f16(kfA[ks], qf[ks], sA, 0, 0, 0);
            sB = __builtin_amdgcn_mfma_f32_32x32x16_f16(kfB[ks], qf[ks], sB, 0, 0, 0);
        }

        // ---- causal mask (last iteration only)
        if (it == niter - 1) {
            #pragma unroll
            for (int r = 0; r < 16; ++r) {
                const int off = (r & 3) + 8 * (r >> 2) + 4 * hi;
                if (kvb + off > q)      sA[r] = -1e30f;
                if (kvb + 32 + off > q) sB[r] = -1e30f;
            }
        }

        // ---- online softmax (exp2 domain), in-register row reduce
        float pmax = sA[0];
        #pragma unroll
        for (int r = 1; r < 16; ++r) pmax = fmaxf(pmax, sA[r]);
        #pragma unroll
        for (int r = 0; r < 16; ++r) pmax = fmaxf(pmax, sB[r]);
        pmax = fmaxf(pmax, __shfl_xor(pmax, 32));

        if (!__all(pmax - m <= 11.0f)) {   // defer-max: skip rescale if small
            const float mnew = fmaxf(m, pmax);
            const float alpha = exp2f(m - mnew);
            m = mnew;
            l *= alpha;
            #pragma unroll
            for (int r = 0; r < 16; ++r) { o0v[r] *= alpha; o1v[r] *= alpha; }
        }
        float rs = 0.f;
        #pragma unroll
        for (int r = 0; r < 16; ++r) { const float p = exp2f(sA[r] - m); sA[r] = p; rs += p; }
        #pragma unroll
        for (int r = 0; r < 16; ++r) { const float p = exp2f(sB[r] - m); sB[r] = p; rs += p; }
        rs += __shfl_xor(rs, 32);
        l += rs;

        // ---- pack P -> PV B-frags (col=q lane-local; kv needs half-swap)
        // slot ks2 regs: a-part = regs 8*ks2+0..3 (kv 16ks2+{0..3}+4hi),
        //                b-part = regs 8*ks2+4..7 (kv 16ks2+{8..11}+4hi)
        H8 pfA[2], pfB[2];
        #pragma unroll
        for (int ks2 = 0; ks2 < 2; ++ks2) {
            {
                const u32 ua0 = pkrtz_u32(sA[8*ks2+0], sA[8*ks2+1]);
                const u32 ua1 = pkrtz_u32(sA[8*ks2+2], sA[8*ks2+3]);
                const u32 ub0 = pkrtz_u32(sA[8*ks2+4], sA[8*ks2+5]);
                const u32 ub1 = pkrtz_u32(sA[8*ks2+6], sA[8*ks2+7]);
                const u32 xa0 = (u32)__shfl_xor((int)ua0, 32);
                const u32 xa1 = (u32)__shfl_xor((int)ua1, 32);
                const u32 xb0 = (u32)__shfl_xor((int)ub0, 32);
                const u32 xb1 = (u32)__shfl_xor((int)ub1, 32);
                pfA[ks2].u[0] = hi ? xb0 : ua0;
                pfA[ks2].u[1] = hi ? xb1 : ua1;
                pfA[ks2].u[2] = hi ? ub0 : xa0;
                pfA[ks2].u[3] = hi ? ub1 : xa1;
            }
            {
                const u32 ua0 = pkrtz_u32(sB[8*ks2+0], sB[8*ks2+1]);
                const u32 ua1 = pkrtz_u32(sB[8*ks2+2], sB[8*ks2+3]);
                const u32 ub0 = pkrtz_u32(sB[8*ks2+4], sB[8*ks2+5]);
                const u32 ub1 = pkrtz_u32(sB[8*ks2+6], sB[8*ks2+7]);
                const u32 xa0 = (u32)__shfl_xor((int)ua0, 32);
                const u32 xa1 = (u32)__shfl_xor((int)ua1, 32);
                const u32 xb0 = (u32)__shfl_xor((int)ub0, 32);
                const u32 xb1 = (u32)__shfl_xor((int)ub1, 32);
                pfB[ks2].u[0] = hi ? xb0 : ua0;
                pfB[ks2].u[1] = hi ? xb1 : ua1;
                pfB[ks2].u[2] = hi ? ub0 : xa0;
                pfB[ks2].u[3] = hi ? ub1 : xa1;
            }
        }

        // ---- PV: O^T[d][q] += V^T · P̂
        #pragma unroll
        for (int ks2 = 0; ks2 < 2; ++ks2) {
            o0v = __builtin_amdgcn_mfma_f32_32x32x16_f16(vf[0][0][ks2], pfA[ks2].v, o0v, 0, 0, 0);
            o1v = __builtin_amdgcn_mfma_f32_32x32x16_f16(vf[0][1][ks2], pfA[ks2].v, o1v, 0, 0, 0);
            o0v = __builtin_amdgcn_mfma_f32_32x32x16_f16(vf[1][0][ks2], pfB[ks2].v, o0v, 0, 0, 0);
            o1v = __builtin_amdgcn_mfma_f32_32x32x16_f16(vf[1][1][ks2], pfB[ks2].v, o1v, 0, 0, 0);
        }
    }

    // ---- epilogue: O^T[d][q] -> att[q][h*64+d], normalize by l
    const float inv = 1.0f / l;
    _Float16* ap = att + (size_t)q * DM + h * DH + 4 * hi;
    #pragma unroll
    for (int g = 0; g < 4; ++g) {
        half4v w0 = { (_Float16)(o0v[4*g+0] * inv), (_Float16)(o0v[4*g+1] * inv),
                      (_Float16)(o0v[4*g+2] * inv), (_Float16)(o0v[4*g+3] * inv) };
        half4v w1 = { (_Float16)(o1v[4*g+0] * inv), (_Float16)(o1v[4*g+1] * inv),
                      (_Float16)(o1v[4*g+2] * inv), (_Float16)(o1v[4*g+3] * inv) };
        *(half4v*)(ap + 8 * g)      = w0;
        *(half4v*)(ap + 32 + 8 * g) = w1;
    }
}

// ---------------------------------------------------------------------------
extern "C" void kernel_launch(void* const* d_in, const int* in_sizes, int n_in,
                              void* d_out, int out_size, void* d_ws, size_t ws_size,
                              hipStream_t stream) {
    const float* x      = (const float*)d_in[0];
    const float* w_qkv  = (const float*)d_in[1];
    const float* w_proj = (const float*)d_in[2];
    const float* b_proj = (const float*)d_in[3];
    float* out = (float*)d_out;

    _Float16* wsb = (_Float16*)d_ws;
    const size_t XS = (size_t)T_SEQ * DM;
    const size_t HS = (size_t)NH * T_SEQ * DH;
    _Float16* xh     = wsb;
    _Float16* wqkvT  = xh + XS;
    _Float16* wprojT = wqkvT + (size_t)NC * DM;
    _Float16* q      = wprojT + (size_t)DM * DM;
    _Float16* k      = q + HS;
    _Float16* v      = k + HS;
    _Float16* vt     = v + HS;
    _Float16* att    = vt + HS;

    convert_x_kernel<<<dim3(1536), 256, 0, stream>>>(x, xh);
    transpose_convert_kernel<<<dim3(36, 12), 256, 0, stream>>>(w_qkv, wqkvT, DM, NC);
    transpose_convert_kernel<<<dim3(12, 12), 256, 0, stream>>>(w_proj, wprojT, DM, DM);
    qkv_mfma_kernel<<<dim3(576), 256, 0, stream>>>(xh, wqkvT, q, k, v);
    vt_kernel<<<dim3(64, NH), 256, 0, stream>>>(v, vt);
    attn_mfma32_kernel<<<dim3(1536), 64, 0, stream>>>(q, k, vt, att);
    proj_mfma_kernel<<<dim3(192), 256, 0, stream>>>(att, wprojT, b_proj, out);
}

// Round 6
// 169.858 us; speedup vs baseline: 6.5283x; 1.0370x over previous
//
#include <hip/hip_runtime.h>

#define T_SEQ 4096
#define DM    768
#define NH    12
#define DH    64
#define NC    2304   // 3 * DM

using half8  = __attribute__((ext_vector_type(8))) _Float16;
using half4v = __attribute__((ext_vector_type(4))) _Float16;
using f32x4  = __attribute__((ext_vector_type(4))) float;
using f32x16 = __attribute__((ext_vector_type(16))) float;
typedef unsigned int u32;

union H8 { half8 v; u32 u[4]; };

// cvt_pkrtz returns __fp16 ext_vector(2); bit-cast straight to u32.
__device__ __forceinline__ u32 pkrtz_u32(float a, float b) {
    return __builtin_bit_cast(u32, __builtin_amdgcn_cvt_pkrtz(a, b));
}

__device__ __forceinline__ void async_copy16(void* lds, const void* g) {
    __builtin_amdgcn_global_load_lds(
        (const __attribute__((address_space(1))) u32*)g,
        (__attribute__((address_space(3))) u32*)lds, 16, 0, 0);
}

// ---------------------------------------------------------------------------
// x (fp32) -> xh (fp16)
// ---------------------------------------------------------------------------
__global__ __launch_bounds__(256)
void convert_x_kernel(const float* __restrict__ x, _Float16* __restrict__ xh) {
    const size_t i = ((size_t)blockIdx.x * 256 + threadIdx.x) * 8;
    float4 a = *(const float4*)(x + i);
    float4 b = *(const float4*)(x + i + 4);
    half8 o = { (_Float16)a.x, (_Float16)a.y, (_Float16)a.z, (_Float16)a.w,
                (_Float16)b.x, (_Float16)b.y, (_Float16)b.z, (_Float16)b.w };
    *(half8*)(xh + i) = o;
}

// ---------------------------------------------------------------------------
// src [R][C] fp32 -> dst [C][R] fp16 (weight transpose+convert)
// ---------------------------------------------------------------------------
__global__ __launch_bounds__(256)
void transpose_convert_kernel(const float* __restrict__ src,
                              _Float16* __restrict__ dst, int R, int C) {
    __shared__ _Float16 tile[64][72];
    const int tid = threadIdx.x;
    const int tc0 = blockIdx.x * 64;
    const int tr0 = blockIdx.y * 64;
    const int r = tid >> 2, c4 = (tid & 3) * 16;
    const float* sp = src + (size_t)(tr0 + r) * C + tc0 + c4;
    #pragma unroll
    for (int j = 0; j < 16; j += 4) {
        float4 t4 = *(const float4*)(sp + j);
        tile[r][c4 + j + 0] = (_Float16)t4.x;
        tile[r][c4 + j + 1] = (_Float16)t4.y;
        tile[r][c4 + j + 2] = (_Float16)t4.z;
        tile[r][c4 + j + 3] = (_Float16)t4.w;
    }
    __syncthreads();
    const int c = tid >> 2, r4 = (tid & 3) * 16;
    half8 o0, o1;
    #pragma unroll
    for (int j = 0; j < 8; ++j) o0[j] = tile[r4 + j][c];
    #pragma unroll
    for (int j = 0; j < 8; ++j) o1[j] = tile[r4 + 8 + j][c];
    _Float16* dp = dst + (size_t)(tc0 + c) * R + tr0 + r4;
    *(half8*)(dp) = o0;
    *(half8*)(dp + 8) = o1;
}

// ---------------------------------------------------------------------------
// fp16 MFMA GEMM (m97 structure)
// ---------------------------------------------------------------------------
__global__ __launch_bounds__(256, 2)
void qkv_mfma_kernel(const _Float16* __restrict__ A,
                     const _Float16* __restrict__ Bt,
                     _Float16* __restrict__ q, _Float16* __restrict__ k,
                     _Float16* __restrict__ v) {
    __shared__ _Float16 Alds[128 * 64];
    __shared__ _Float16 Blds[128 * 64];
    const int tid  = threadIdx.x;
    const int lane = tid & 63;
    const int w    = tid >> 6;
    const int wr = w >> 1, wc = w & 1;
    const int lrow = lane >> 4, lcol = lane & 15;

    const int bid  = blockIdx.x;                    // 576 = 8 * 72
    const int virt = (bid & 7) * 72 + (bid >> 3);
    const int cbn  = virt % 18, rbn = virt / 18;

    const _Float16* Ag = A  + (size_t)rbn * 128 * DM;
    const _Float16* Bg = Bt + (size_t)cbn * 128 * DM;

    int srow[4], scol[4];
    #pragma unroll
    for (int i = 0; i < 4; ++i) {
        const int idx = i * 256 + tid;
        srow[i] = idx >> 3;
        scol[i] = ((idx & 7) ^ (srow[i] & 7)) * 8;
    }

    f32x4 acc[4][4];
    #pragma unroll
    for (int mf = 0; mf < 4; ++mf)
        #pragma unroll
        for (int nf = 0; nf < 4; ++nf) acc[mf][nf] = (f32x4){0.f, 0.f, 0.f, 0.f};

    for (int kt = 0; kt < DM / 64; ++kt) {
        const int k0 = kt * 64;
        __syncthreads();
        #pragma unroll
        for (int i = 0; i < 4; ++i) {
            async_copy16((char*)Alds + (i * 256 + w * 64) * 16,
                         Ag + (size_t)srow[i] * DM + k0 + scol[i]);
            async_copy16((char*)Blds + (i * 256 + w * 64) * 16,
                         Bg + (size_t)srow[i] * DM + k0 + scol[i]);
        }
        __syncthreads();
        #pragma unroll
        for (int kh = 0; kh < 2; ++kh) {
            half8 af[4], bf[4];
            const int ag = kh * 4 + lrow;
            #pragma unroll
            for (int f = 0; f < 4; ++f) {
                const int ar = wr * 64 + f * 16 + lcol;
                af[f] = *(const half8*)((const char*)Alds +
                          ar * 128 + ((ag ^ (ar & 7)) << 4));
                const int br = wc * 64 + f * 16 + lcol;
                bf[f] = *(const half8*)((const char*)Blds +
                          br * 128 + ((ag ^ (br & 7)) << 4));
            }
            #pragma unroll
            for (int mf = 0; mf < 4; ++mf)
                #pragma unroll
                for (int nf = 0; nf < 4; ++nf)
                    acc[mf][nf] = __builtin_amdgcn_mfma_f32_16x16x32_f16(
                        af[mf], bf[nf], acc[mf][nf], 0, 0, 0);
        }
    }

    #pragma unroll
    for (int nf = 0; nf < 4; ++nf) {
        const int n = cbn * 128 + wc * 64 + nf * 16 + lcol;
        const int head  = n / 192;
        const int which = (n >> 6) % 3;
        const int d = n & 63;
        _Float16* dst = (which == 0) ? q : (which == 1) ? k : v;
        const float sc = (which == 0) ? 0.18033688011112042f : 1.0f;
        dst += (size_t)head * T_SEQ * DH + d;
        #pragma unroll
        for (int mf = 0; mf < 4; ++mf) {
            const int t0 = rbn * 128 + wr * 64 + mf * 16 + lrow * 4;
            #pragma unroll
            for (int r = 0; r < 4; ++r)
                dst[(size_t)(t0 + r) * DH] = (_Float16)(acc[mf][nf][r] * sc);
        }
    }
}

__global__ __launch_bounds__(256, 2)
void proj_mfma_kernel(const _Float16* __restrict__ A,
                      const _Float16* __restrict__ Bt,
                      const float* __restrict__ bias, float* __restrict__ out) {
    __shared__ _Float16 Alds[128 * 64];
    __shared__ _Float16 Blds[128 * 64];
    const int tid  = threadIdx.x;
    const int lane = tid & 63;
    const int w    = tid >> 6;
    const int wr = w >> 1, wc = w & 1;
    const int lrow = lane >> 4, lcol = lane & 15;

    const int bid  = blockIdx.x;                    // 192 = 8 * 24
    const int virt = (bid & 7) * 24 + (bid >> 3);
    const int cbn  = virt % 6, rbn = virt / 6;

    const _Float16* Ag = A  + (size_t)rbn * 128 * DM;
    const _Float16* Bg = Bt + (size_t)cbn * 128 * DM;

    int srow[4], scol[4];
    #pragma unroll
    for (int i = 0; i < 4; ++i) {
        const int idx = i * 256 + tid;
        srow[i] = idx >> 3;
        scol[i] = ((idx & 7) ^ (srow[i] & 7)) * 8;
    }

    f32x4 acc[4][4];
    #pragma unroll
    for (int mf = 0; mf < 4; ++mf)
        #pragma unroll
        for (int nf = 0; nf < 4; ++nf) acc[mf][nf] = (f32x4){0.f, 0.f, 0.f, 0.f};

    for (int kt = 0; kt < DM / 64; ++kt) {
        const int k0 = kt * 64;
        __syncthreads();
        #pragma unroll
        for (int i = 0; i < 4; ++i) {
            async_copy16((char*)Alds + (i * 256 + w * 64) * 16,
                         Ag + (size_t)srow[i] * DM + k0 + scol[i]);
            async_copy16((char*)Blds + (i * 256 + w * 64) * 16,
                         Bg + (size_t)srow[i] * DM + k0 + scol[i]);
        }
        __syncthreads();
        #pragma unroll
        for (int kh = 0; kh < 2; ++kh) {
            half8 af[4], bf[4];
            const int ag = kh * 4 + lrow;
            #pragma unroll
            for (int f = 0; f < 4; ++f) {
                const int ar = wr * 64 + f * 16 + lcol;
                af[f] = *(const half8*)((const char*)Alds +
                          ar * 128 + ((ag ^ (ar & 7)) << 4));
                const int br = wc * 64 + f * 16 + lcol;
                bf[f] = *(const half8*)((const char*)Blds +
                          br * 128 + ((ag ^ (br & 7)) << 4));
            }
            #pragma unroll
            for (int mf = 0; mf < 4; ++mf)
                #pragma unroll
                for (int nf = 0; nf < 4; ++nf)
                    acc[mf][nf] = __builtin_amdgcn_mfma_f32_16x16x32_f16(
                        af[mf], bf[nf], acc[mf][nf], 0, 0, 0);
        }
    }

    #pragma unroll
    for (int nf = 0; nf < 4; ++nf) {
        const int n = cbn * 128 + wc * 64 + nf * 16 + lcol;
        const float b = bias[n];
        #pragma unroll
        for (int mf = 0; mf < 4; ++mf) {
            const int t0 = rbn * 128 + wr * 64 + mf * 16 + lrow * 4;
            #pragma unroll
            for (int r = 0; r < 4; ++r)
                out[(size_t)(t0 + r) * DM + n] = acc[mf][nf][r] + b;
        }
    }
}

// ---------------------------------------------------------------------------
// V [h][t][d] -> Vt [h][d][t] (fp16)
// ---------------------------------------------------------------------------
__global__ __launch_bounds__(256)
void vt_kernel(const _Float16* __restrict__ v, _Float16* __restrict__ vt) {
    __shared__ _Float16 tile[64][65];
    const int tid = threadIdx.x;
    const int tb = blockIdx.x, h = blockIdx.y;
    const int r = tid >> 2, c0 = (tid & 3) * 16;
    const _Float16* src = v + ((size_t)h * T_SEQ + tb * 64 + r) * 64 + c0;
    half8 a0 = *(const half8*)(src);
    half8 a1 = *(const half8*)(src + 8);
    #pragma unroll
    for (int j = 0; j < 8; ++j) tile[r][c0 + j] = a0[j];
    #pragma unroll
    for (int j = 0; j < 8; ++j) tile[r][c0 + 8 + j] = a1[j];
    __syncthreads();
    const int d = tid >> 2, t0 = (tid & 3) * 16;
    half8 o0, o1;
    #pragma unroll
    for (int j = 0; j < 8; ++j) o0[j] = tile[t0 + j][d];
    #pragma unroll
    for (int j = 0; j < 8; ++j) o1[j] = tile[t0 + 8 + j][d];
    _Float16* dst = vt + ((size_t)h * 64 + d) * T_SEQ + tb * 64 + t0;
    *(half8*)(dst) = o0;
    *(half8*)(dst + 8) = o1;
}

// ---------------------------------------------------------------------------
// Flash attention, swapped-operand 32x32x16 MFMA, zero LDS / zero barriers,
// K register-prefetch double-buffer (ILP — 1.5 waves/SIMD means TLP can't
// hide the K-load -> S-MFMA dependent chain; prefetch covers it with the
// previous iteration's softmax+pack+PV), setprio around MFMA clusters (T5).
// ---------------------------------------------------------------------------
__global__ __launch_bounds__(64)
void attn_mfma32_kernel(const _Float16* __restrict__ qg,
                        const _Float16* __restrict__ kg,
                        const _Float16* __restrict__ vtg,
                        _Float16* __restrict__ att) {
    const int lane = threadIdx.x & 63;
    const int l31  = lane & 31;
    const int hi   = lane >> 5;

    const int bid = blockIdx.x;
    const int h   = bid % NH;
    const int c   = 127 - bid / NH;      // q-chunk, heavy first
    const int q0  = c * 32;
    const int q   = q0 + l31;            // this lane's q-row
    const int niter = c / 2 + 1;
    const int maxkvb = (niter - 1) * 64;

    const _Float16* Qh = qg  + ((size_t)h * T_SEQ + q) * DH;
    const _Float16* Kh = kg  + (size_t)h * T_SEQ * DH;
    const _Float16* Vh = vtg + (size_t)h * DH * T_SEQ;

    // Q fragments (B operand): col=lane&31=q, k(d) = 16*ks + hi*8 + j
    half8 qf[4];
    #pragma unroll
    for (int ks = 0; ks < 4; ++ks)
        qf[ks] = *(const half8*)(Qh + ks * 16 + hi * 8);

    f32x16 o0v = {}, o1v = {};           // O^T d-tiles 0..31, 32..63
    float m = -1e30f, l = 0.f;

    // K buffers: [0..3] = rows kvb+l31 (tile A), [4..7] = rows kvb+32+l31 (B)
    half8 kbuf0[8], kbuf1[8];
    #pragma unroll
    for (int ks = 0; ks < 4; ++ks) {
        kbuf0[ks]     = *(const half8*)(Kh + (size_t)l31 * DH + ks * 16 + hi * 8);
        kbuf0[4 + ks] = *(const half8*)(Kh + (size_t)(32 + l31) * DH + ks * 16 + hi * 8);
    }

    auto body = [&](int it, half8* kc, half8* kn) {
        const int kvb = it * 64;
        const int nkvb = (kvb + 64 <= maxkvb) ? kvb + 64 : maxkvb;  // clamp

        // ---- prefetch next K tile (in flight during S-MFMA stall)
        #pragma unroll
        for (int ks = 0; ks < 4; ++ks) {
            kn[ks]     = *(const half8*)(Kh + (size_t)(nkvb + l31) * DH + ks * 16 + hi * 8);
            kn[4 + ks] = *(const half8*)(Kh + (size_t)(nkvb + 32 + l31) * DH + ks * 16 + hi * 8);
        }
        // ---- V^T frags (A operand): row=lane&31=d, k(kv)=16ks2+hi*8+j
        half8 vf[2][2][2];   // [kv-tile][dt][ks2]
        #pragma unroll
        for (int t = 0; t < 2; ++t)
            #pragma unroll
            for (int dt = 0; dt < 2; ++dt)
                #pragma unroll
                for (int ks2 = 0; ks2 < 2; ++ks2)
                    vf[t][dt][ks2] = *(const half8*)(Vh +
                        (size_t)(dt * 32 + l31) * T_SEQ +
                        kvb + t * 32 + ks2 * 16 + hi * 8);

        // ---- S^T = K Q^T
        f32x16 sA = {}, sB = {};
        __builtin_amdgcn_s_setprio(1);
        #pragma unroll
        for (int ks = 0; ks < 4; ++ks) {
            sA = __builtin_amdgcn_mfma_f32_32x32x16_f16(kc[ks],     qf[ks], sA, 0, 0, 0);
            sB = __builtin_amdgcn_mfma_f32_32x32x16_f16(kc[4 + ks], qf[ks], sB, 0, 0, 0);
        }
        __builtin_amdgcn_s_setprio(0);

        // ---- causal mask (last iteration only)
        if (it == niter - 1) {
            #pragma unroll
            for (int r = 0; r < 16; ++r) {
                const int off = (r & 3) + 8 * (r >> 2) + 4 * hi;
                if (kvb + off > q)      sA[r] = -1e30f;
                if (kvb + 32 + off > q) sB[r] = -1e30f;
            }
        }

        // ---- online softmax (exp2 domain), in-register row reduce
        float pmax = sA[0];
        #pragma unroll
        for (int r = 1; r < 16; ++r) pmax = fmaxf(pmax, sA[r]);
        #pragma unroll
        for (int r = 0; r < 16; ++r) pmax = fmaxf(pmax, sB[r]);
        pmax = fmaxf(pmax, __shfl_xor(pmax, 32));

        if (!__all(pmax - m <= 11.0f)) {   // defer-max: skip rescale if small
            const float mnew = fmaxf(m, pmax);
            const float alpha = exp2f(m - mnew);
            m = mnew;
            l *= alpha;
            #pragma unroll
            for (int r = 0; r < 16; ++r) { o0v[r] *= alpha; o1v[r] *= alpha; }
        }
        float rs = 0.f;
        #pragma unroll
        for (int r = 0; r < 16; ++r) { const float p = exp2f(sA[r] - m); sA[r] = p; rs += p; }
        #pragma unroll
        for (int r = 0; r < 16; ++r) { const float p = exp2f(sB[r] - m); sB[r] = p; rs += p; }
        rs += __shfl_xor(rs, 32);
        l += rs;

        // ---- pack P -> PV B-frags (col=q lane-local; kv needs half-swap)
        H8 pfA[2], pfB[2];
        #pragma unroll
        for (int ks2 = 0; ks2 < 2; ++ks2) {
            {
                const u32 ua0 = pkrtz_u32(sA[8*ks2+0], sA[8*ks2+1]);
                const u32 ua1 = pkrtz_u32(sA[8*ks2+2], sA[8*ks2+3]);
                const u32 ub0 = pkrtz_u32(sA[8*ks2+4], sA[8*ks2+5]);
                const u32 ub1 = pkrtz_u32(sA[8*ks2+6], sA[8*ks2+7]);
                const u32 xa0 = (u32)__shfl_xor((int)ua0, 32);
                const u32 xa1 = (u32)__shfl_xor((int)ua1, 32);
                const u32 xb0 = (u32)__shfl_xor((int)ub0, 32);
                const u32 xb1 = (u32)__shfl_xor((int)ub1, 32);
                pfA[ks2].u[0] = hi ? xb0 : ua0;
                pfA[ks2].u[1] = hi ? xb1 : ua1;
                pfA[ks2].u[2] = hi ? ub0 : xa0;
                pfA[ks2].u[3] = hi ? ub1 : xa1;
            }
            {
                const u32 ua0 = pkrtz_u32(sB[8*ks2+0], sB[8*ks2+1]);
                const u32 ua1 = pkrtz_u32(sB[8*ks2+2], sB[8*ks2+3]);
                const u32 ub0 = pkrtz_u32(sB[8*ks2+4], sB[8*ks2+5]);
                const u32 ub1 = pkrtz_u32(sB[8*ks2+6], sB[8*ks2+7]);
                const u32 xa0 = (u32)__shfl_xor((int)ua0, 32);
                const u32 xa1 = (u32)__shfl_xor((int)ua1, 32);
                const u32 xb0 = (u32)__shfl_xor((int)ub0, 32);
                const u32 xb1 = (u32)__shfl_xor((int)ub1, 32);
                pfB[ks2].u[0] = hi ? xb0 : ua0;
                pfB[ks2].u[1] = hi ? xb1 : ua1;
                pfB[ks2].u[2] = hi ? ub0 : xa0;
                pfB[ks2].u[3] = hi ? ub1 : xa1;
            }
        }

        // ---- PV: O^T[d][q] += V^T · P̂
        __builtin_amdgcn_s_setprio(1);
        #pragma unroll
        for (int ks2 = 0; ks2 < 2; ++ks2) {
            o0v = __builtin_amdgcn_mfma_f32_32x32x16_f16(vf[0][0][ks2], pfA[ks2].v, o0v, 0, 0, 0);
            o1v = __builtin_amdgcn_mfma_f32_32x32x16_f16(vf[0][1][ks2], pfA[ks2].v, o1v, 0, 0, 0);
            o0v = __builtin_amdgcn_mfma_f32_32x32x16_f16(vf[1][0][ks2], pfB[ks2].v, o0v, 0, 0, 0);
            o1v = __builtin_amdgcn_mfma_f32_32x32x16_f16(vf[1][1][ks2], pfB[ks2].v, o1v, 0, 0, 0);
        }
        __builtin_amdgcn_s_setprio(0);
    };

    // 2x-unrolled ping-pong so buffer indices stay compile-time (rule #20)
    int it = 0;
    while (true) {
        body(it, kbuf0, kbuf1);
        if (++it >= niter) break;
        body(it, kbuf1, kbuf0);
        if (++it >= niter) break;
    }

    // ---- epilogue: O^T[d][q] -> att[q][h*64+d], normalize by l
    const float inv = 1.0f / l;
    _Float16* ap = att + (size_t)q * DM + h * DH + 4 * hi;
    #pragma unroll
    for (int g = 0; g < 4; ++g) {
        half4v w0 = { (_Float16)(o0v[4*g+0] * inv), (_Float16)(o0v[4*g+1] * inv),
                      (_Float16)(o0v[4*g+2] * inv), (_Float16)(o0v[4*g+3] * inv) };
        half4v w1 = { (_Float16)(o1v[4*g+0] * inv), (_Float16)(o1v[4*g+1] * inv),
                      (_Float16)(o1v[4*g+2] * inv), (_Float16)(o1v[4*g+3] * inv) };
        *(half4v*)(ap + 8 * g)      = w0;
        *(half4v*)(ap + 32 + 8 * g) = w1;
    }
}

// ---------------------------------------------------------------------------
extern "C" void kernel_launch(void* const* d_in, const int* in_sizes, int n_in,
                              void* d_out, int out_size, void* d_ws, size_t ws_size,
                              hipStream_t stream) {
    const float* x      = (const float*)d_in[0];
    const float* w_qkv  = (const float*)d_in[1];
    const float* w_proj = (const float*)d_in[2];
    const float* b_proj = (const float*)d_in[3];
    float* out = (float*)d_out;

    _Float16* wsb = (_Float16*)d_ws;
    const size_t XS = (size_t)T_SEQ * DM;
    const size_t HS = (size_t)NH * T_SEQ * DH;
    _Float16* xh     = wsb;
    _Float16* wqkvT  = xh + XS;
    _Float16* wprojT = wqkvT + (size_t)NC * DM;
    _Float16* q      = wprojT + (size_t)DM * DM;
    _Float16* k      = q + HS;
    _Float16* v      = k + HS;
    _Float16* vt     = v + HS;
    _Float16* att    = vt + HS;

    convert_x_kernel<<<dim3(1536), 256, 0, stream>>>(x, xh);
    transpose_convert_kernel<<<dim3(36, 12), 256, 0, stream>>>(w_qkv, wqkvT, DM, NC);
    transpose_convert_kernel<<<dim3(12, 12), 256, 0, stream>>>(w_proj, wprojT, DM, DM);
    qkv_mfma_kernel<<<dim3(576), 256, 0, stream>>>(xh, wqkvT, q, k, v);
    vt_kernel<<<dim3(64, NH), 256, 0, stream>>>(v, vt);
    attn_mfma32_kernel<<<dim3(1536), 64, 0, stream>>>(q, k, vt, att);
    proj_mfma_kernel<<<dim3(192), 256, 0, stream>>>(att, wprojT, b_proj, out);
}

// Round 7
// 167.671 us; speedup vs baseline: 6.6134x; 1.0130x over previous
//
#include <hip/hip_runtime.h>

#define T_SEQ 4096
#define DM    768
#define NH    12
#define DH    64
#define NC    2304   // 3 * DM

using half8  = __attribute__((ext_vector_type(8))) _Float16;
using half4v = __attribute__((ext_vector_type(4))) _Float16;
using f32x4  = __attribute__((ext_vector_type(4))) float;
using f32x16 = __attribute__((ext_vector_type(16))) float;
typedef unsigned int u32;

union H8 { half8 v; u32 u[4]; };

// cvt_pkrtz returns __fp16 ext_vector(2); bit-cast straight to u32.
__device__ __forceinline__ u32 pkrtz_u32(float a, float b) {
    return __builtin_bit_cast(u32, __builtin_amdgcn_cvt_pkrtz(a, b));
}
__device__ __forceinline__ float asf(u32 x) { return __builtin_bit_cast(float, x); }
__device__ __forceinline__ u32 asu(float x) { return __builtin_bit_cast(u32, x); }

__device__ __forceinline__ void async_copy16(void* lds, const void* g) {
    __builtin_amdgcn_global_load_lds(
        (const __attribute__((address_space(1))) u32*)g,
        (__attribute__((address_space(3))) u32*)lds, 16, 0, 0);
}

// ---------------------------------------------------------------------------
// x (fp32) -> xh (fp16)
// ---------------------------------------------------------------------------
__global__ __launch_bounds__(256)
void convert_x_kernel(const float* __restrict__ x, _Float16* __restrict__ xh) {
    const size_t i = ((size_t)blockIdx.x * 256 + threadIdx.x) * 8;
    float4 a = *(const float4*)(x + i);
    float4 b = *(const float4*)(x + i + 4);
    half8 o = { (_Float16)a.x, (_Float16)a.y, (_Float16)a.z, (_Float16)a.w,
                (_Float16)b.x, (_Float16)b.y, (_Float16)b.z, (_Float16)b.w };
    *(half8*)(xh + i) = o;
}

// ---------------------------------------------------------------------------
// src [R][C] fp32 -> dst [C][R] fp16 (weight transpose+convert)
// ---------------------------------------------------------------------------
__global__ __launch_bounds__(256)
void transpose_convert_kernel(const float* __restrict__ src,
                              _Float16* __restrict__ dst, int R, int C) {
    __shared__ _Float16 tile[64][72];
    const int tid = threadIdx.x;
    const int tc0 = blockIdx.x * 64;
    const int tr0 = blockIdx.y * 64;
    const int r = tid >> 2, c4 = (tid & 3) * 16;
    const float* sp = src + (size_t)(tr0 + r) * C + tc0 + c4;
    #pragma unroll
    for (int j = 0; j < 16; j += 4) {
        float4 t4 = *(const float4*)(sp + j);
        tile[r][c4 + j + 0] = (_Float16)t4.x;
        tile[r][c4 + j + 1] = (_Float16)t4.y;
        tile[r][c4 + j + 2] = (_Float16)t4.z;
        tile[r][c4 + j + 3] = (_Float16)t4.w;
    }
    __syncthreads();
    const int c = tid >> 2, r4 = (tid & 3) * 16;
    half8 o0, o1;
    #pragma unroll
    for (int j = 0; j < 8; ++j) o0[j] = tile[r4 + j][c];
    #pragma unroll
    for (int j = 0; j < 8; ++j) o1[j] = tile[r4 + 8 + j][c];
    _Float16* dp = dst + (size_t)(tc0 + c) * R + tr0 + r4;
    *(half8*)(dp) = o0;
    *(half8*)(dp + 8) = o1;
}

// ---------------------------------------------------------------------------
// fp16 MFMA GEMM (m97 structure)
// ---------------------------------------------------------------------------
__global__ __launch_bounds__(256, 2)
void qkv_mfma_kernel(const _Float16* __restrict__ A,
                     const _Float16* __restrict__ Bt,
                     _Float16* __restrict__ q, _Float16* __restrict__ k,
                     _Float16* __restrict__ v) {
    __shared__ _Float16 Alds[128 * 64];
    __shared__ _Float16 Blds[128 * 64];
    const int tid  = threadIdx.x;
    const int lane = tid & 63;
    const int w    = tid >> 6;
    const int wr = w >> 1, wc = w & 1;
    const int lrow = lane >> 4, lcol = lane & 15;

    const int bid  = blockIdx.x;                    // 576 = 8 * 72
    const int virt = (bid & 7) * 72 + (bid >> 3);
    const int cbn  = virt % 18, rbn = virt / 18;

    const _Float16* Ag = A  + (size_t)rbn * 128 * DM;
    const _Float16* Bg = Bt + (size_t)cbn * 128 * DM;

    int srow[4], scol[4];
    #pragma unroll
    for (int i = 0; i < 4; ++i) {
        const int idx = i * 256 + tid;
        srow[i] = idx >> 3;
        scol[i] = ((idx & 7) ^ (srow[i] & 7)) * 8;
    }

    f32x4 acc[4][4];
    #pragma unroll
    for (int mf = 0; mf < 4; ++mf)
        #pragma unroll
        for (int nf = 0; nf < 4; ++nf) acc[mf][nf] = (f32x4){0.f, 0.f, 0.f, 0.f};

    for (int kt = 0; kt < DM / 64; ++kt) {
        const int k0 = kt * 64;
        __syncthreads();
        #pragma unroll
        for (int i = 0; i < 4; ++i) {
            async_copy16((char*)Alds + (i * 256 + w * 64) * 16,
                         Ag + (size_t)srow[i] * DM + k0 + scol[i]);
            async_copy16((char*)Blds + (i * 256 + w * 64) * 16,
                         Bg + (size_t)srow[i] * DM + k0 + scol[i]);
        }
        __syncthreads();
        #pragma unroll
        for (int kh = 0; kh < 2; ++kh) {
            half8 af[4], bf[4];
            const int ag = kh * 4 + lrow;
            #pragma unroll
            for (int f = 0; f < 4; ++f) {
                const int ar = wr * 64 + f * 16 + lcol;
                af[f] = *(const half8*)((const char*)Alds +
                          ar * 128 + ((ag ^ (ar & 7)) << 4));
                const int br = wc * 64 + f * 16 + lcol;
                bf[f] = *(const half8*)((const char*)Blds +
                          br * 128 + ((ag ^ (br & 7)) << 4));
            }
            #pragma unroll
            for (int mf = 0; mf < 4; ++mf)
                #pragma unroll
                for (int nf = 0; nf < 4; ++nf)
                    acc[mf][nf] = __builtin_amdgcn_mfma_f32_16x16x32_f16(
                        af[mf], bf[nf], acc[mf][nf], 0, 0, 0);
        }
    }

    #pragma unroll
    for (int nf = 0; nf < 4; ++nf) {
        const int n = cbn * 128 + wc * 64 + nf * 16 + lcol;
        const int head  = n / 192;
        const int which = (n >> 6) % 3;
        const int d = n & 63;
        _Float16* dst = (which == 0) ? q : (which == 1) ? k : v;
        const float sc = (which == 0) ? 0.18033688011112042f : 1.0f;
        dst += (size_t)head * T_SEQ * DH + d;
        #pragma unroll
        for (int mf = 0; mf < 4; ++mf) {
            const int t0 = rbn * 128 + wr * 64 + mf * 16 + lrow * 4;
            #pragma unroll
            for (int r = 0; r < 4; ++r)
                dst[(size_t)(t0 + r) * DH] = (_Float16)(acc[mf][nf][r] * sc);
        }
    }
}

__global__ __launch_bounds__(256, 2)
void proj_mfma_kernel(const _Float16* __restrict__ A,
                      const _Float16* __restrict__ Bt,
                      const float* __restrict__ bias, float* __restrict__ out) {
    __shared__ _Float16 Alds[128 * 64];
    __shared__ _Float16 Blds[128 * 64];
    const int tid  = threadIdx.x;
    const int lane = tid & 63;
    const int w    = tid >> 6;
    const int wr = w >> 1, wc = w & 1;
    const int lrow = lane >> 4, lcol = lane & 15;

    const int bid  = blockIdx.x;                    // 192 = 8 * 24
    const int virt = (bid & 7) * 24 + (bid >> 3);
    const int cbn  = virt % 6, rbn = virt / 6;

    const _Float16* Ag = A  + (size_t)rbn * 128 * DM;
    const _Float16* Bg = Bt + (size_t)cbn * 128 * DM;

    int srow[4], scol[4];
    #pragma unroll
    for (int i = 0; i < 4; ++i) {
        const int idx = i * 256 + tid;
        srow[i] = idx >> 3;
        scol[i] = ((idx & 7) ^ (srow[i] & 7)) * 8;
    }

    f32x4 acc[4][4];
    #pragma unroll
    for (int mf = 0; mf < 4; ++mf)
        #pragma unroll
        for (int nf = 0; nf < 4; ++nf) acc[mf][nf] = (f32x4){0.f, 0.f, 0.f, 0.f};

    for (int kt = 0; kt < DM / 64; ++kt) {
        const int k0 = kt * 64;
        __syncthreads();
        #pragma unroll
        for (int i = 0; i < 4; ++i) {
            async_copy16((char*)Alds + (i * 256 + w * 64) * 16,
                         Ag + (size_t)srow[i] * DM + k0 + scol[i]);
            async_copy16((char*)Blds + (i * 256 + w * 64) * 16,
                         Bg + (size_t)srow[i] * DM + k0 + scol[i]);
        }
        __syncthreads();
        #pragma unroll
        for (int kh = 0; kh < 2; ++kh) {
            half8 af[4], bf[4];
            const int ag = kh * 4 + lrow;
            #pragma unroll
            for (int f = 0; f < 4; ++f) {
                const int ar = wr * 64 + f * 16 + lcol;
                af[f] = *(const half8*)((const char*)Alds +
                          ar * 128 + ((ag ^ (ar & 7)) << 4));
                const int br = wc * 64 + f * 16 + lcol;
                bf[f] = *(const half8*)((const char*)Blds +
                          br * 128 + ((ag ^ (br & 7)) << 4));
            }
            #pragma unroll
            for (int mf = 0; mf < 4; ++mf)
                #pragma unroll
                for (int nf = 0; nf < 4; ++nf)
                    acc[mf][nf] = __builtin_amdgcn_mfma_f32_16x16x32_f16(
                        af[mf], bf[nf], acc[mf][nf], 0, 0, 0);
        }
    }

    #pragma unroll
    for (int nf = 0; nf < 4; ++nf) {
        const int n = cbn * 128 + wc * 64 + nf * 16 + lcol;
        const float b = bias[n];
        #pragma unroll
        for (int mf = 0; mf < 4; ++mf) {
            const int t0 = rbn * 128 + wr * 64 + mf * 16 + lrow * 4;
            #pragma unroll
            for (int r = 0; r < 4; ++r)
                out[(size_t)(t0 + r) * DM + n] = acc[mf][nf][r] + b;
        }
    }
}

// ---------------------------------------------------------------------------
// V [h][t][d] -> Vt [h][d][t] (fp16)
// ---------------------------------------------------------------------------
__global__ __launch_bounds__(256)
void vt_kernel(const _Float16* __restrict__ v, _Float16* __restrict__ vt) {
    __shared__ _Float16 tile[64][65];
    const int tid = threadIdx.x;
    const int tb = blockIdx.x, h = blockIdx.y;
    const int r = tid >> 2, c0 = (tid & 3) * 16;
    const _Float16* src = v + ((size_t)h * T_SEQ + tb * 64 + r) * 64 + c0;
    half8 a0 = *(const half8*)(src);
    half8 a1 = *(const half8*)(src + 8);
    #pragma unroll
    for (int j = 0; j < 8; ++j) tile[r][c0 + j] = a0[j];
    #pragma unroll
    for (int j = 0; j < 8; ++j) tile[r][c0 + 8 + j] = a1[j];
    __syncthreads();
    const int d = tid >> 2, t0 = (tid & 3) * 16;
    half8 o0, o1;
    #pragma unroll
    for (int j = 0; j < 8; ++j) o0[j] = tile[t0 + j][d];
    #pragma unroll
    for (int j = 0; j < 8; ++j) o1[j] = tile[t0 + 8 + j][d];
    _Float16* dst = vt + ((size_t)h * 64 + d) * T_SEQ + tb * 64 + t0;
    *(half8*)(dst) = o0;
    *(half8*)(dst + 8) = o1;
}

// ---------------------------------------------------------------------------
// Flash attention, swapped-operand 32x32x16 MFMA, zero LDS / zero barriers.
// This round: ALL cross-half lane exchanges via v_permlane32_swap (VALU,
// ~4 cyc) instead of __shfl_xor(32) (ds_bpermute, ~120 cyc LDS pipe) — the
// 18 LDS shuffles/iter were the serial chain. Max/sum reduces tree-ified.
//   permlane32_swap(a,b) -> r: r[0] = {a.lo | b.lo}, r[1] = {a.hi | b.hi}
//   (r[0][i] = i<32 ? a[i] : b[i-32];  r[1][i] = i<32 ? a[i+32] : b[i])
// With a==b==x: fmax(r[0],r[1])[i] = fmax(x[i], x[i^32]) in every lane.
// ---------------------------------------------------------------------------
__global__ __launch_bounds__(64)
void attn_mfma32_kernel(const _Float16* __restrict__ qg,
                        const _Float16* __restrict__ kg,
                        const _Float16* __restrict__ vtg,
                        _Float16* __restrict__ att) {
    const int lane = threadIdx.x & 63;
    const int l31  = lane & 31;
    const int hi   = lane >> 5;

    const int bid = blockIdx.x;
    const int h   = bid % NH;
    const int c   = 127 - bid / NH;      // q-chunk, heavy first
    const int q0  = c * 32;
    const int q   = q0 + l31;            // this lane's q-row
    const int niter = c / 2 + 1;
    const int maxkvb = (niter - 1) * 64;

    const _Float16* Qh = qg  + ((size_t)h * T_SEQ + q) * DH;
    const _Float16* Kh = kg  + (size_t)h * T_SEQ * DH;
    const _Float16* Vh = vtg + (size_t)h * DH * T_SEQ;

    // Q fragments (B operand): col=lane&31=q, k(d) = 16*ks + hi*8 + j
    half8 qf[4];
    #pragma unroll
    for (int ks = 0; ks < 4; ++ks)
        qf[ks] = *(const half8*)(Qh + ks * 16 + hi * 8);

    f32x16 o0v = {}, o1v = {};           // O^T d-tiles 0..31, 32..63
    float m = -1e30f, l = 0.f;

    // K buffers: [0..3] = rows kvb+l31 (tile A), [4..7] = rows kvb+32+l31 (B)
    half8 kbuf0[8], kbuf1[8];
    #pragma unroll
    for (int ks = 0; ks < 4; ++ks) {
        kbuf0[ks]     = *(const half8*)(Kh + (size_t)l31 * DH + ks * 16 + hi * 8);
        kbuf0[4 + ks] = *(const half8*)(Kh + (size_t)(32 + l31) * DH + ks * 16 + hi * 8);
    }

    auto body = [&](int it, half8* kc, half8* kn) {
        const int kvb = it * 64;
        const int nkvb = (kvb + 64 <= maxkvb) ? kvb + 64 : maxkvb;  // clamp

        // ---- prefetch next K tile (in flight during S-MFMA + softmax)
        #pragma unroll
        for (int ks = 0; ks < 4; ++ks) {
            kn[ks]     = *(const half8*)(Kh + (size_t)(nkvb + l31) * DH + ks * 16 + hi * 8);
            kn[4 + ks] = *(const half8*)(Kh + (size_t)(nkvb + 32 + l31) * DH + ks * 16 + hi * 8);
        }
        // ---- V^T frags (A operand): row=lane&31=d, k(kv)=16ks2+hi*8+j
        half8 vf[2][2][2];   // [kv-tile][dt][ks2]
        #pragma unroll
        for (int t = 0; t < 2; ++t)
            #pragma unroll
            for (int dt = 0; dt < 2; ++dt)
                #pragma unroll
                for (int ks2 = 0; ks2 < 2; ++ks2)
                    vf[t][dt][ks2] = *(const half8*)(Vh +
                        (size_t)(dt * 32 + l31) * T_SEQ +
                        kvb + t * 32 + ks2 * 16 + hi * 8);

        // ---- S^T = K Q^T
        f32x16 sA = {}, sB = {};
        __builtin_amdgcn_s_setprio(1);
        #pragma unroll
        for (int ks = 0; ks < 4; ++ks) {
            sA = __builtin_amdgcn_mfma_f32_32x32x16_f16(kc[ks],     qf[ks], sA, 0, 0, 0);
            sB = __builtin_amdgcn_mfma_f32_32x32x16_f16(kc[4 + ks], qf[ks], sB, 0, 0, 0);
        }
        __builtin_amdgcn_s_setprio(0);

        // ---- causal mask (last iteration only)
        if (it == niter - 1) {
            #pragma unroll
            for (int r = 0; r < 16; ++r) {
                const int off = (r & 3) + 8 * (r >> 2) + 4 * hi;
                if (kvb + off > q)      sA[r] = -1e30f;
                if (kvb + 32 + off > q) sB[r] = -1e30f;
            }
        }

        // ---- online softmax (exp2 domain): tree max, permlane cross-half
        float t8[8];
        #pragma unroll
        for (int r = 0; r < 8; ++r)
            t8[r] = fmaxf(fmaxf(sA[r], sA[r + 8]), fmaxf(sB[r], sB[r + 8]));
        float t4a = fmaxf(t8[0], t8[4]), t4b = fmaxf(t8[1], t8[5]);
        float t4c = fmaxf(t8[2], t8[6]), t4d = fmaxf(t8[3], t8[7]);
        float pmax = fmaxf(fmaxf(t4a, t4b), fmaxf(t4c, t4d));
        {
            auto r = __builtin_amdgcn_permlane32_swap(asu(pmax), asu(pmax), false, false);
            pmax = fmaxf(asf(r[0]), asf(r[1]));
        }

        if (!__all(pmax - m <= 11.0f)) {   // defer-max: skip rescale if small
            const float mnew = fmaxf(m, pmax);
            const float alpha = exp2f(m - mnew);
            m = mnew;
            l *= alpha;
            #pragma unroll
            for (int r = 0; r < 16; ++r) { o0v[r] *= alpha; o1v[r] *= alpha; }
        }
        #pragma unroll
        for (int r = 0; r < 16; ++r) sA[r] = exp2f(sA[r] - m);
        #pragma unroll
        for (int r = 0; r < 16; ++r) sB[r] = exp2f(sB[r] - m);
        float s8[8];
        #pragma unroll
        for (int r = 0; r < 8; ++r)
            s8[r] = (sA[r] + sA[r + 8]) + (sB[r] + sB[r + 8]);
        float rsum = ((s8[0] + s8[4]) + (s8[1] + s8[5])) +
                     ((s8[2] + s8[6]) + (s8[3] + s8[7]));
        {
            auto r = __builtin_amdgcn_permlane32_swap(asu(rsum), asu(rsum), false, false);
            rsum = asf(r[0]) + asf(r[1]);
        }
        l += rsum;

        // ---- pack P -> PV B-frags: 4 cvt_pkrtz + 2 permlane per group
        H8 pfA[2], pfB[2];
        #pragma unroll
        for (int ks2 = 0; ks2 < 2; ++ks2) {
            {
                const u32 a0 = pkrtz_u32(sA[8*ks2+0], sA[8*ks2+1]);
                const u32 a1 = pkrtz_u32(sA[8*ks2+2], sA[8*ks2+3]);
                const u32 b0 = pkrtz_u32(sA[8*ks2+4], sA[8*ks2+5]);
                const u32 b1 = pkrtz_u32(sA[8*ks2+6], sA[8*ks2+7]);
                auto r0 = __builtin_amdgcn_permlane32_swap(a0, b0, false, false);
                auto r1 = __builtin_amdgcn_permlane32_swap(a1, b1, false, false);
                pfA[ks2].u[0] = r0[0];
                pfA[ks2].u[1] = r1[0];
                pfA[ks2].u[2] = r0[1];
                pfA[ks2].u[3] = r1[1];
            }
            {
                const u32 a0 = pkrtz_u32(sB[8*ks2+0], sB[8*ks2+1]);
                const u32 a1 = pkrtz_u32(sB[8*ks2+2], sB[8*ks2+3]);
                const u32 b0 = pkrtz_u32(sB[8*ks2+4], sB[8*ks2+5]);
                const u32 b1 = pkrtz_u32(sB[8*ks2+6], sB[8*ks2+7]);
                auto r0 = __builtin_amdgcn_permlane32_swap(a0, b0, false, false);
                auto r1 = __builtin_amdgcn_permlane32_swap(a1, b1, false, false);
                pfB[ks2].u[0] = r0[0];
                pfB[ks2].u[1] = r1[0];
                pfB[ks2].u[2] = r0[1];
                pfB[ks2].u[3] = r1[1];
            }
        }

        // ---- PV: O^T[d][q] += V^T · P̂
        __builtin_amdgcn_s_setprio(1);
        #pragma unroll
        for (int ks2 = 0; ks2 < 2; ++ks2) {
            o0v = __builtin_amdgcn_mfma_f32_32x32x16_f16(vf[0][0][ks2], pfA[ks2].v, o0v, 0, 0, 0);
            o1v = __builtin_amdgcn_mfma_f32_32x32x16_f16(vf[0][1][ks2], pfA[ks2].v, o1v, 0, 0, 0);
            o0v = __builtin_amdgcn_mfma_f32_32x32x16_f16(vf[1][0][ks2], pfB[ks2].v, o0v, 0, 0, 0);
            o1v = __builtin_amdgcn_mfma_f32_32x32x16_f16(vf[1][1][ks2], pfB[ks2].v, o1v, 0, 0, 0);
        }
        __builtin_amdgcn_s_setprio(0);
    };

    // 2x-unrolled ping-pong so buffer indices stay compile-time (rule #20)
    int it = 0;
    while (true) {
        body(it, kbuf0, kbuf1);
        if (++it >= niter) break;
        body(it, kbuf1, kbuf0);
        if (++it >= niter) break;
    }

    // ---- epilogue: O^T[d][q] -> att[q][h*64+d], normalize by l
    const float inv = 1.0f / l;
    _Float16* ap = att + (size_t)q * DM + h * DH + 4 * hi;
    #pragma unroll
    for (int g = 0; g < 4; ++g) {
        half4v w0 = { (_Float16)(o0v[4*g+0] * inv), (_Float16)(o0v[4*g+1] * inv),
                      (_Float16)(o0v[4*g+2] * inv), (_Float16)(o0v[4*g+3] * inv) };
        half4v w1 = { (_Float16)(o1v[4*g+0] * inv), (_Float16)(o1v[4*g+1] * inv),
                      (_Float16)(o1v[4*g+2] * inv), (_Float16)(o1v[4*g+3] * inv) };
        *(half4v*)(ap + 8 * g)      = w0;
        *(half4v*)(ap + 32 + 8 * g) = w1;
    }
}

// ---------------------------------------------------------------------------
extern "C" void kernel_launch(void* const* d_in, const int* in_sizes, int n_in,
                              void* d_out, int out_size, void* d_ws, size_t ws_size,
                              hipStream_t stream) {
    const float* x      = (const float*)d_in[0];
    const float* w_qkv  = (const float*)d_in[1];
    const float* w_proj = (const float*)d_in[2];
    const float* b_proj = (const float*)d_in[3];
    float* out = (float*)d_out;

    _Float16* wsb = (_Float16*)d_ws;
    const size_t XS = (size_t)T_SEQ * DM;
    const size_t HS = (size_t)NH * T_SEQ * DH;
    _Float16* xh     = wsb;
    _Float16* wqkvT  = xh + XS;
    _Float16* wprojT = wqkvT + (size_t)NC * DM;
    _Float16* q      = wprojT + (size_t)DM * DM;
    _Float16* k      = q + HS;
    _Float16* v      = k + HS;
    _Float16* vt     = v + HS;
    _Float16* att    = vt + HS;

    convert_x_kernel<<<dim3(1536), 256, 0, stream>>>(x, xh);
    transpose_convert_kernel<<<dim3(36, 12), 256, 0, stream>>>(w_qkv, wqkvT, DM, NC);
    transpose_convert_kernel<<<dim3(12, 12), 256, 0, stream>>>(w_proj, wprojT, DM, DM);
    qkv_mfma_kernel<<<dim3(576), 256, 0, stream>>>(xh, wqkvT, q, k, v);
    vt_kernel<<<dim3(64, NH), 256, 0, stream>>>(v, vt);
    attn_mfma32_kernel<<<dim3(1536), 64, 0, stream>>>(q, k, vt, att);
    proj_mfma_kernel<<<dim3(192), 256, 0, stream>>>(att, wprojT, b_proj, out);
}